// Round 9
// baseline (1216.287 us; speedup 1.0000x reference)
//
#include <hip/hip_runtime.h>

#define L_SEQ 4096
#define NSTEP 2047
#define ST_W  (-0.000625f)   // -LR * (2/H) = -0.01/16

// ws layout (bytes):
//  [0,      8192)   table  64x32 f32
//  [8192,  24576)   G      64x64 f32
//  [24576, 26624)   Z0     64x8  f32
//  [26624, 26628)   wacc   f32
//  [28672, 94208)   flags  256 rows x 64 words (bit ts of word t>>5 = wr_t)

// ---------------------------------------------------------------------------
// Cross-lane reduction helpers (VALU pipe). Layout: i = lane&7, g = lane>>3.
// ---------------------------------------------------------------------------
__device__ __forceinline__ void redi4(float& a, float& b, float& c, float& d) {
    asm volatile(
        "s_nop 1\n\t"
        "v_add_f32_dpp %0, %0, %0 quad_perm:[1,0,3,2] row_mask:0xf bank_mask:0xf bound_ctrl:0\n\t"
        "v_add_f32_dpp %1, %1, %1 quad_perm:[1,0,3,2] row_mask:0xf bank_mask:0xf bound_ctrl:0\n\t"
        "v_add_f32_dpp %2, %2, %2 quad_perm:[1,0,3,2] row_mask:0xf bank_mask:0xf bound_ctrl:0\n\t"
        "v_add_f32_dpp %3, %3, %3 quad_perm:[1,0,3,2] row_mask:0xf bank_mask:0xf bound_ctrl:0\n\t"
        "v_add_f32_dpp %0, %0, %0 quad_perm:[2,3,0,1] row_mask:0xf bank_mask:0xf bound_ctrl:0\n\t"
        "v_add_f32_dpp %1, %1, %1 quad_perm:[2,3,0,1] row_mask:0xf bank_mask:0xf bound_ctrl:0\n\t"
        "v_add_f32_dpp %2, %2, %2 quad_perm:[2,3,0,1] row_mask:0xf bank_mask:0xf bound_ctrl:0\n\t"
        "v_add_f32_dpp %3, %3, %3 quad_perm:[2,3,0,1] row_mask:0xf bank_mask:0xf bound_ctrl:0\n\t"
        "v_add_f32_dpp %0, %0, %0 row_half_mirror row_mask:0xf bank_mask:0xf bound_ctrl:0\n\t"
        "v_add_f32_dpp %1, %1, %1 row_half_mirror row_mask:0xf bank_mask:0xf bound_ctrl:0\n\t"
        "v_add_f32_dpp %2, %2, %2 row_half_mirror row_mask:0xf bank_mask:0xf bound_ctrl:0\n\t"
        "v_add_f32_dpp %3, %3, %3 row_half_mirror row_mask:0xf bank_mask:0xf bound_ctrl:0"
        : "+v"(a), "+v"(b), "+v"(c), "+v"(d));
}

__device__ __forceinline__ float redg1(float x) {
    float t;
    asm volatile(
        "s_nop 1\n\t"
        "v_add_f32_dpp %0, %0, %0 row_ror:8 row_mask:0xf bank_mask:0xf bound_ctrl:0\n\t"
        "s_nop 1\n\t"
        "v_mov_b32 %1, %0\n\t"
        "s_nop 1\n\t"
        "v_permlane16_swap_b32 %1, %0\n\t"
        "s_nop 0\n\t"
        "v_add_f32 %0, %0, %1\n\t"
        "s_nop 1\n\t"
        "v_mov_b32 %1, %0\n\t"
        "s_nop 1\n\t"
        "v_permlane32_swap_b32 %1, %0\n\t"
        "s_nop 0\n\t"
        "v_add_f32 %0, %0, %1"
        : "+v"(x), "=&v"(t));
    return x;
}

// select Z[r] among 8 regs; r is wave-uniform in fact — assert it with
// readfirstlane so the ?: masks land in SGPR pairs (valid cndmask operand).
__device__ __forceinline__ float sel8u(const float* Z, int r) {
    r = __builtin_amdgcn_readfirstlane(r);
    unsigned long long m0 = (r & 1) ? ~0ull : 0ull;
    unsigned long long m1 = (r & 2) ? ~0ull : 0ull;
    unsigned long long m2 = (r & 4) ? ~0ull : 0ull;
    float a0, a1, a2, a3, b0, b1v, res;
    asm("v_cndmask_b32 %0, %1, %2, %3" : "=v"(a0) : "v"(Z[0]), "v"(Z[1]), "s"(m0));
    asm("v_cndmask_b32 %0, %1, %2, %3" : "=v"(a1) : "v"(Z[2]), "v"(Z[3]), "s"(m0));
    asm("v_cndmask_b32 %0, %1, %2, %3" : "=v"(a2) : "v"(Z[4]), "v"(Z[5]), "s"(m0));
    asm("v_cndmask_b32 %0, %1, %2, %3" : "=v"(a3) : "v"(Z[6]), "v"(Z[7]), "s"(m0));
    asm("v_cndmask_b32 %0, %1, %2, %3" : "=v"(b0)  : "v"(a0), "v"(a1), "s"(m1));
    asm("v_cndmask_b32 %0, %1, %2, %3" : "=v"(b1v) : "v"(a2), "v"(a3), "s"(m1));
    asm("v_cndmask_b32 %0, %1, %2, %3" : "=v"(res) : "v"(b0), "v"(b1v), "s"(m2));
    return res;
}

__device__ __forceinline__ float bperm_row(int tok, int i4, float v) {
    int addr = ((tok & 56) << 2) | i4;
    return __int_as_float(__builtin_amdgcn_ds_bpermute(addr, __float_as_int(v)));
}

__device__ __forceinline__ int rli(int x, int l) {
    return __builtin_amdgcn_readlane(x, l);
}

// ---------------------------------------------------------------------------
// Phase A: table[v] = LN(e_v + MLP(e_v)); G = table·tableᵀ; Z0 = fc1_w·tableᵀ
// ---------------------------------------------------------------------------
__global__ __launch_bounds__(64) void build_kernel(
    const float* __restrict__ embed, const float* __restrict__ ff1_w,
    const float* __restrict__ ff1_b, const float* __restrict__ ff2_w,
    const float* __restrict__ ff2_b, const float* __restrict__ ln_g,
    const float* __restrict__ ln_b, const float* __restrict__ fc1_w,
    float* __restrict__ table, float* __restrict__ G, float* __restrict__ Z0)
{
    __shared__ float tl[64][32];
    const int v = threadIdx.x;
    float h[32], f[32];
#pragma unroll
    for (int j = 0; j < 32; ++j) { h[j] = embed[v * 32 + j]; f[j] = 0.f; }
    for (int k = 0; k < 64; ++k) {
        float z = ff1_b[k];
#pragma unroll
        for (int j = 0; j < 32; ++j) z += h[j] * ff1_w[k * 32 + j];
        z = fmaxf(z, 0.f);
#pragma unroll
        for (int j = 0; j < 32; ++j) f[j] += z * ff2_w[j * 64 + k];
    }
    float x[32], mu = 0.f;
#pragma unroll
    for (int j = 0; j < 32; ++j) { x[j] = h[j] + f[j] + ff2_b[j]; mu += x[j]; }
    mu *= (1.f / 32.f);
    float var = 0.f;
#pragma unroll
    for (int j = 0; j < 32; ++j) { float d = x[j] - mu; var += d * d; }
    var *= (1.f / 32.f);
    const float inv = rsqrtf(var + 1e-5f);
    float tv[32];
#pragma unroll
    for (int j = 0; j < 32; ++j) {
        tv[j] = ln_g[j] * (x[j] - mu) * inv + ln_b[j];
        tl[v][j] = tv[j];
        table[v * 32 + j] = tv[j];
    }
    __syncthreads();
    for (int u = 0; u < 64; ++u) {
        float acc = 0.f;
#pragma unroll
        for (int j = 0; j < 32; ++j) acc += tv[j] * tl[u][j];
        G[v * 64 + u] = acc;
    }
    for (int i = 0; i < 8; ++i) {
        float acc = 0.f;
#pragma unroll
        for (int j = 0; j < 32; ++j) acc += fc1_w[i * 32 + j] * tv[j];
        Z0[v * 8 + i] = acc;
    }
}

// ---------------------------------------------------------------------------
// Phase B1: PARALLEL write-gate kernel. One 256-thread block per batch row.
// ---------------------------------------------------------------------------
__global__ __launch_bounds__(256) void flags_kernel(
    const int* __restrict__ seq, const float* __restrict__ Gg,
    unsigned int* __restrict__ flags, float* __restrict__ wacc)
{
    __shared__ float Gs[4096];
    __shared__ float P[64][64];
    __shared__ int   kt[2048];
    __shared__ float Aa[2048];
    __shared__ float Ws[2048];
    __shared__ float red[256];
    const int tid = threadIdx.x, b = blockIdx.x;
    for (int idx = tid; idx < 4096; idx += 256) Gs[idx] = Gg[idx];
    const int2* sp2 = reinterpret_cast<const int2*>(seq + b * L_SEQ);
    for (int j = tid; j < 2048; j += 256) kt[j] = sp2[j].x;
    __syncthreads();

    for (int idx = tid; idx < 4096; idx += 256) {
        const int c = idx >> 6, u = idx & 63;
        const int base = c * 32;
        float s = 0.f;
#pragma unroll 4
        for (int j = 0; j < 32; ++j) s += Gs[kt[base + j] * 64 + u];
        P[c][u] = s;
    }
    __syncthreads();
    if (tid < 64) {
        float acc = 0.f;
        for (int c = 0; c < 64; ++c) { float p = P[c][tid]; P[c][tid] = acc; acc += p; }
    }
    __syncthreads();
    for (int t = tid; t < NSTEP; t += 256) {
        const int c = t >> 5, base = c << 5;
        const int ktt = kt[t];
        float a = P[c][ktt];
        for (int s = base; s < t; ++s) a += Gs[kt[s] * 64 + ktt];
        Aa[t] = a;
        Ws[t] = 2.f * a + Gs[ktt * 65];
    }
    __syncthreads();
    float loc[8], tot = 0.f;
    const int base8 = tid * 8;
#pragma unroll
    for (int j = 0; j < 8; ++j) {
        float v = (base8 + j < NSTEP) ? Ws[base8 + j] : 0.f;
        loc[j] = tot; tot += v;
    }
    red[tid] = tot;
    __syncthreads();
    float run = tot;
    for (int off = 1; off < 256; off <<= 1) {
        float add = (tid >= off) ? red[tid - off] : 0.f;
        __syncthreads();
        run += add; red[tid] = run;
        __syncthreads();
    }
    const float excl = run - tot;
    __syncthreads();
#pragma unroll
    for (int j = 0; j < 8; ++j) {
        const int t = base8 + j;
        if (t < NSTEP) {
            const float u_t = excl + loc[j];
            const float tf = (float)t;
            const int ktt = kt[t];
            const float r = fmaf(tf * tf, Gs[ktt * 65] - 16.f, u_t)
                            - 2.f * tf * Aa[t];
            Ws[t] = (t == 0 || r > 0.f) ? 1.f : 0.f;
        }
    }
    __syncthreads();
    int cnt = 0;
    if (tid < 64) {
        unsigned int w = 0;
        for (int j = 0; j < 32; ++j) {
            const int t = tid * 32 + j;
            if (t < NSTEP && Ws[t] != 0.f) w |= 1u << j;
        }
        flags[b * 64 + tid] = w;
        cnt = __popc(w);
    }
    red[tid] = (float)cnt;
    __syncthreads();
    if (tid == 0) {
        float s = 0.f;
        for (int j = 0; j < 64; ++j) s += red[j];
        atomicAdd(wacc, s);
    }
}

// ---------------------------------------------------------------------------
// Phase B2: fast-weight scan. 1024-thread blocks = 16 waves = 16 rows,
// 16 blocks -> 4 waves per SIMD (stall-hiding via co-residency).
// Lane (i=lane&7, g=lane>>3): Zr[r]=Z[8g+r][i], W2[4g+c][i], b2[4g+c].
// Depth-1 DS prefetch; no SMEM/global in the loop.
// ---------------------------------------------------------------------------
__global__ __launch_bounds__(1024) void scan_kernel(
    const int* __restrict__ seq, const float* __restrict__ tableg,
    const float* __restrict__ Gg, const float* __restrict__ Z0g,
    const float* __restrict__ fc1_b, const float* __restrict__ fc2_w,
    const float* __restrict__ fc2_b, const float* __restrict__ out_w,
    const float* __restrict__ out_b, const unsigned int* __restrict__ flags,
    float* __restrict__ out)
{
    __shared__ float Gs[4096];
    __shared__ float tabs[2048];
    __shared__ float ctxs[16][32];
    const int tid = threadIdx.x;
    const int wave = __builtin_amdgcn_readfirstlane(tid >> 6);
    const int lane = tid & 63;
    const int row = blockIdx.x * 16 + wave;
    const int i = lane & 7, g = lane >> 3;
    const int l31 = lane & 31;
    const int i4 = i << 2;
    for (int idx = tid; idx < 4096; idx += 1024) Gs[idx] = Gg[idx];
    for (int idx = tid; idx < 2048; idx += 1024) tabs[idx] = tableg[idx];
    __syncthreads();
    const float4* tab4 = reinterpret_cast<const float4*>(tabs);

    // --- state ---
    float Zr[8];
#pragma unroll
    for (int r = 0; r < 8; ++r) Zr[r] = Z0g[(8 * g + r) * 8 + i];
    float b1 = fc1_b[i];
    float W2r0 = fc2_w[(4 * g + 0) * 8 + i];
    float W2r1 = fc2_w[(4 * g + 1) * 8 + i];
    float W2r2 = fc2_w[(4 * g + 2) * 8 + i];
    float W2r3 = fc2_w[(4 * g + 3) * 8 + i];
    float4 b2r = reinterpret_cast<const float4*>(fc2_b)[g];

    const int2* sp2 = reinterpret_cast<const int2*>(seq + row * L_SEQ);
    const unsigned int fwv = flags[row * 64 + lane];   // lane l holds word l

    int2 cbA = sp2[l31];
    int2 cbB = sp2[32 + l31];
    int2 cbC = sp2[64 + l31];

    int k0t = rli(cbA.x, 0);
    int v0t = rli(cbA.y, 0);
    int kn1 = rli(cbA.x, 1);
    int vn1 = rli(cbA.y, 1);

    // --- prologue (one-time latency) ---
    const float4* gp0 = reinterpret_cast<const float4*>(Gs + k0t * 64 + 8 * g);
    float4 GaC = gp0[0], GbC = gp0[1];
    float4 vc0 = tab4[v0t * 8 + g];
    float gbIn = Gs[k0t * 64 + kn1];                 // G[k0][k1]
    float yb = bperm_row(k0t, i4, sel8u(Zr, k0t & 7)) + b1;
    float es0 = b2r.x - vc0.x, es1 = b2r.y - vc0.y;
    float es2 = b2r.z - vc0.z, es3 = b2r.w - vc0.w;
    float c_prev = 0.f, gB1c = 0.f;
    unsigned int fw = 0;

#pragma unroll 2
    for (int t = 0; t < NSTEP; ++t) {
        const int ts = t & 31;
        if (ts == 0) {
            fw = (unsigned int)rli((int)fwv, t >> 5);
            if (t) {
                cbA = cbB; cbB = cbC;
                int c2 = (t >> 5) + 2; if (c2 > 63) c2 = 63;
                cbC = sp2[c2 * 32 + l31];
            }
        }
        const float st = ((fw >> ts) & 1u) ? ST_W : 0.f;

        // tokens for t+2
        const int idx2 = (t + 2) & 31;
        const bool hi2 = (ts >= 30);
        int cx = hi2 ? cbB.x : cbA.x;
        int cy = hi2 ? cbB.y : cbA.y;
        const int kn2 = rli(cx, idx2);
        const int vn2 = rli(cy, idx2);

        // bperm for step t+1 (reads Z_{t-1}; corrected via gB1c next step)
        float ynv = bperm_row(kn1, i4, sel8u(Zr, kn1 & 7));

        // DS prefetch (depth 1): rows for step t+1
        const float4* gpn = reinterpret_cast<const float4*>(Gs + kn1 * 64 + 8 * g);
        float4 GaN = gpn[0], GbN = gpn[1];
        float4 vcN = tab4[vn1 * 8 + g];
        float gbNew = Gs[kn1 * 64 + kn2];            // G[k_{t+1}][k_{t+2}]

        // --- critical path (step t) ---
        const float z1 = fmaf(c_prev, gB1c, yb);
        const float a  = fmaxf(z1, 0.f);
        float p0 = W2r0 * a, p1 = W2r1 * a, p2 = W2r2 * a, p3 = W2r3 * a;
        redi4(p0, p1, p2, p3);
        const float dp0 = p0 + es0, dp1 = p1 + es1;
        const float dp2 = p2 + es2, dp3 = p3 + es3;
        float q = redg1(fmaf(W2r0, dp0, W2r1 * dp1) + fmaf(W2r2, dp2, W2r3 * dp3));
        const float c = (z1 > 0.f) ? st * q : 0.f;

        // --- updates (off critical path) ---
        const float u0 = st * dp0, u1 = st * dp1;
        const float u2 = st * dp2, u3 = st * dp3;
        W2r0 = fmaf(u0, a, W2r0); W2r1 = fmaf(u1, a, W2r1);
        W2r2 = fmaf(u2, a, W2r2); W2r3 = fmaf(u3, a, W2r3);
        b2r.x += u0; b2r.y += u1; b2r.z += u2; b2r.w += u3;
        Zr[0] = fmaf(c, GaC.x, Zr[0]); Zr[1] = fmaf(c, GaC.y, Zr[1]);
        Zr[2] = fmaf(c, GaC.z, Zr[2]); Zr[3] = fmaf(c, GaC.w, Zr[3]);
        Zr[4] = fmaf(c, GbC.x, Zr[4]); Zr[5] = fmaf(c, GbC.y, Zr[5]);
        Zr[6] = fmaf(c, GbC.z, Zr[6]); Zr[7] = fmaf(c, GbC.w, Zr[7]);
        const float ybN = ynv + b1;                  // pre-update b1
        b1 += c;
        es0 = b2r.x - vcN.x; es1 = b2r.y - vcN.y;    // es for step t+1
        es2 = b2r.z - vcN.z; es3 = b2r.w - vcN.w;

        // --- rotate ---
        yb = ybN; c_prev = c; gB1c = gbIn + 1.f; gbIn = gbNew;
        GaC = GaN; GbC = GbN;
        kn1 = kn2; vn1 = vn2;
    }

    // --- query/context ---
    const int tq = __builtin_amdgcn_readfirstlane(seq[row * L_SEQ + (L_SEQ - 1)]);
    float yq = bperm_row(tq, i4, sel8u(Zr, tq & 7));
    const float zq = yq + b1;
    const float aq = fmaxf(zq, 0.f);
    float c0 = W2r0 * aq, c1 = W2r1 * aq, c2 = W2r2 * aq, c3 = W2r3 * aq;
    redi4(c0, c1, c2, c3);
    if (i == 0) {
        ctxs[wave][4 * g + 0] = c0 + b2r.x;
        ctxs[wave][4 * g + 1] = c1 + b2r.y;
        ctxs[wave][4 * g + 2] = c2 + b2r.z;
        ctxs[wave][4 * g + 3] = c3 + b2r.w;
    }
    // same-wave LDS write->read: LDS ops execute in program order per wave
    float acc = out_b[lane];
#pragma unroll
    for (int j = 0; j < 32; ++j) acc += ctxs[wave][j] * out_w[lane * 32 + j];
    out[row * 64 + lane] = acc;
}

__global__ void finalize_kernel(const float* __restrict__ wacc,
                                float* __restrict__ out)
{
    out[16384] = wacc[0] * (1.0f / 524032.0f);   // / (B * n) = 256 * 2047
}

// ---------------------------------------------------------------------------
extern "C" void kernel_launch(void* const* d_in, const int* in_sizes, int n_in,
                              void* d_out, int out_size, void* d_ws, size_t ws_size,
                              hipStream_t stream)
{
    const int*   seq   = (const int*)  d_in[0];
    const float* embed = (const float*)d_in[1];
    const float* ff1_w = (const float*)d_in[2];
    const float* ff1_b = (const float*)d_in[3];
    const float* ff2_w = (const float*)d_in[4];
    const float* ff2_b = (const float*)d_in[5];
    const float* ln_g  = (const float*)d_in[6];
    const float* ln_b  = (const float*)d_in[7];
    const float* fc1_w = (const float*)d_in[8];
    const float* fc1_b = (const float*)d_in[9];
    const float* fc2_w = (const float*)d_in[10];
    const float* fc2_b = (const float*)d_in[11];
    const float* out_w = (const float*)d_in[12];
    const float* out_b = (const float*)d_in[13];

    float* out = (float*)d_out;
    char* ws = (char*)d_ws;
    float*        table = (float*)(ws + 0);
    float*        G     = (float*)(ws + 8192);
    float*        Z0    = (float*)(ws + 24576);
    float*        wacc  = (float*)(ws + 26624);
    unsigned int* flags = (unsigned int*)(ws + 28672);

    hipMemsetAsync(wacc, 0, sizeof(float), stream);
    hipLaunchKernelGGL(build_kernel, dim3(1), dim3(64), 0, stream,
                       embed, ff1_w, ff1_b, ff2_w, ff2_b, ln_g, ln_b, fc1_w,
                       table, G, Z0);
    hipLaunchKernelGGL(flags_kernel, dim3(256), dim3(256), 0, stream,
                       seq, G, flags, wacc);
    hipLaunchKernelGGL(scan_kernel, dim3(16), dim3(1024), 0, stream,
                       seq, table, G, Z0, fc1_b, fc2_w, fc2_b,
                       out_w, out_b, flags, out);
    hipLaunchKernelGGL(finalize_kernel, dim3(1), dim3(1), 0, stream, wacc, out);
}

// Round 10
// 472.252 us; speedup vs baseline: 2.5755x; 2.5755x over previous
//
#include <hip/hip_runtime.h>

#define L_SEQ 4096
#define NSTEP 2047
#define ST_W  (-0.000625f)   // -LR * (2/H) = -0.01/16

// ws layout (bytes):
//  [0,      8192)   table  64x32 f32
//  [8192,  24576)   G      64x64 f32
//  [24576, 26624)   Z0     64x8  f32
//  [26624, 26628)   wacc   f32
//  [28672, 94208)   flags  256 rows x 64 words (bit ts of word t>>5 = wr_t)

// ---------------------------------------------------------------------------
// Cross-lane reduction helpers (VALU pipe). Layout: i = lane&7, g = lane>>3.
// ---------------------------------------------------------------------------
__device__ __forceinline__ void redi4(float& a, float& b, float& c, float& d) {
    asm volatile(
        "s_nop 1\n\t"
        "v_add_f32_dpp %0, %0, %0 quad_perm:[1,0,3,2] row_mask:0xf bank_mask:0xf bound_ctrl:0\n\t"
        "v_add_f32_dpp %1, %1, %1 quad_perm:[1,0,3,2] row_mask:0xf bank_mask:0xf bound_ctrl:0\n\t"
        "v_add_f32_dpp %2, %2, %2 quad_perm:[1,0,3,2] row_mask:0xf bank_mask:0xf bound_ctrl:0\n\t"
        "v_add_f32_dpp %3, %3, %3 quad_perm:[1,0,3,2] row_mask:0xf bank_mask:0xf bound_ctrl:0\n\t"
        "v_add_f32_dpp %0, %0, %0 quad_perm:[2,3,0,1] row_mask:0xf bank_mask:0xf bound_ctrl:0\n\t"
        "v_add_f32_dpp %1, %1, %1 quad_perm:[2,3,0,1] row_mask:0xf bank_mask:0xf bound_ctrl:0\n\t"
        "v_add_f32_dpp %2, %2, %2 quad_perm:[2,3,0,1] row_mask:0xf bank_mask:0xf bound_ctrl:0\n\t"
        "v_add_f32_dpp %3, %3, %3 quad_perm:[2,3,0,1] row_mask:0xf bank_mask:0xf bound_ctrl:0\n\t"
        "v_add_f32_dpp %0, %0, %0 row_half_mirror row_mask:0xf bank_mask:0xf bound_ctrl:0\n\t"
        "v_add_f32_dpp %1, %1, %1 row_half_mirror row_mask:0xf bank_mask:0xf bound_ctrl:0\n\t"
        "v_add_f32_dpp %2, %2, %2 row_half_mirror row_mask:0xf bank_mask:0xf bound_ctrl:0\n\t"
        "v_add_f32_dpp %3, %3, %3 row_half_mirror row_mask:0xf bank_mask:0xf bound_ctrl:0"
        : "+v"(a), "+v"(b), "+v"(c), "+v"(d));
}

__device__ __forceinline__ float redg1(float x) {
    float t;
    asm volatile(
        "s_nop 1\n\t"
        "v_add_f32_dpp %0, %0, %0 row_ror:8 row_mask:0xf bank_mask:0xf bound_ctrl:0\n\t"
        "s_nop 1\n\t"
        "v_mov_b32 %1, %0\n\t"
        "s_nop 1\n\t"
        "v_permlane16_swap_b32 %1, %0\n\t"
        "s_nop 0\n\t"
        "v_add_f32 %0, %0, %1\n\t"
        "s_nop 1\n\t"
        "v_mov_b32 %1, %0\n\t"
        "s_nop 1\n\t"
        "v_permlane32_swap_b32 %1, %0\n\t"
        "s_nop 0\n\t"
        "v_add_f32 %0, %0, %1"
        : "+v"(x), "=&v"(t));
    return x;
}

// select Z[r] among 8 regs; r is wave-uniform (SGPR): masks built on SALU,
// exactly 7 v_cndmask on the VALU.
__device__ __forceinline__ float sel8u(const float* Z, int r) {
    unsigned long long m0 = (r & 1) ? ~0ull : 0ull;
    unsigned long long m1 = (r & 2) ? ~0ull : 0ull;
    unsigned long long m2 = (r & 4) ? ~0ull : 0ull;
    float a0, a1, a2, a3, b0, b1v, res;
    asm("v_cndmask_b32 %0, %1, %2, %3" : "=v"(a0) : "v"(Z[0]), "v"(Z[1]), "s"(m0));
    asm("v_cndmask_b32 %0, %1, %2, %3" : "=v"(a1) : "v"(Z[2]), "v"(Z[3]), "s"(m0));
    asm("v_cndmask_b32 %0, %1, %2, %3" : "=v"(a2) : "v"(Z[4]), "v"(Z[5]), "s"(m0));
    asm("v_cndmask_b32 %0, %1, %2, %3" : "=v"(a3) : "v"(Z[6]), "v"(Z[7]), "s"(m0));
    asm("v_cndmask_b32 %0, %1, %2, %3" : "=v"(b0)  : "v"(a0), "v"(a1), "s"(m1));
    asm("v_cndmask_b32 %0, %1, %2, %3" : "=v"(b1v) : "v"(a2), "v"(a3), "s"(m1));
    asm("v_cndmask_b32 %0, %1, %2, %3" : "=v"(res) : "v"(b0), "v"(b1v), "s"(m2));
    return res;
}

__device__ __forceinline__ float bperm_row(int tok, int i4, float v) {
    int addr = ((tok & 56) << 2) | i4;
    return __int_as_float(__builtin_amdgcn_ds_bpermute(addr, __float_as_int(v)));
}

__device__ __forceinline__ int rli(int x, int l) {
    return __builtin_amdgcn_readlane(x, l);
}

// ---------------------------------------------------------------------------
// Phase A: table[v] = LN(e_v + MLP(e_v)); G = table·tableᵀ; Z0 = fc1_w·tableᵀ
// ---------------------------------------------------------------------------
__global__ __launch_bounds__(64) void build_kernel(
    const float* __restrict__ embed, const float* __restrict__ ff1_w,
    const float* __restrict__ ff1_b, const float* __restrict__ ff2_w,
    const float* __restrict__ ff2_b, const float* __restrict__ ln_g,
    const float* __restrict__ ln_b, const float* __restrict__ fc1_w,
    float* __restrict__ table, float* __restrict__ G, float* __restrict__ Z0)
{
    __shared__ float tl[64][32];
    const int v = threadIdx.x;
    float h[32], f[32];
#pragma unroll
    for (int j = 0; j < 32; ++j) { h[j] = embed[v * 32 + j]; f[j] = 0.f; }
    for (int k = 0; k < 64; ++k) {
        float z = ff1_b[k];
#pragma unroll
        for (int j = 0; j < 32; ++j) z += h[j] * ff1_w[k * 32 + j];
        z = fmaxf(z, 0.f);
#pragma unroll
        for (int j = 0; j < 32; ++j) f[j] += z * ff2_w[j * 64 + k];
    }
    float x[32], mu = 0.f;
#pragma unroll
    for (int j = 0; j < 32; ++j) { x[j] = h[j] + f[j] + ff2_b[j]; mu += x[j]; }
    mu *= (1.f / 32.f);
    float var = 0.f;
#pragma unroll
    for (int j = 0; j < 32; ++j) { float d = x[j] - mu; var += d * d; }
    var *= (1.f / 32.f);
    const float inv = rsqrtf(var + 1e-5f);
    float tv[32];
#pragma unroll
    for (int j = 0; j < 32; ++j) {
        tv[j] = ln_g[j] * (x[j] - mu) * inv + ln_b[j];
        tl[v][j] = tv[j];
        table[v * 32 + j] = tv[j];
    }
    __syncthreads();
    for (int u = 0; u < 64; ++u) {
        float acc = 0.f;
#pragma unroll
        for (int j = 0; j < 32; ++j) acc += tv[j] * tl[u][j];
        G[v * 64 + u] = acc;
    }
    for (int i = 0; i < 8; ++i) {
        float acc = 0.f;
#pragma unroll
        for (int j = 0; j < 32; ++j) acc += fc1_w[i * 32 + j] * tv[j];
        Z0[v * 8 + i] = acc;
    }
}

// ---------------------------------------------------------------------------
// Phase B1: PARALLEL write-gate kernel. One 256-thread block per batch row.
// ---------------------------------------------------------------------------
__global__ __launch_bounds__(256) void flags_kernel(
    const int* __restrict__ seq, const float* __restrict__ Gg,
    unsigned int* __restrict__ flags, float* __restrict__ wacc)
{
    __shared__ float Gs[4096];
    __shared__ float P[64][64];
    __shared__ int   kt[2048];
    __shared__ float Aa[2048];
    __shared__ float Ws[2048];
    __shared__ float red[256];
    const int tid = threadIdx.x, b = blockIdx.x;
    for (int idx = tid; idx < 4096; idx += 256) Gs[idx] = Gg[idx];
    const int2* sp2 = reinterpret_cast<const int2*>(seq + b * L_SEQ);
    for (int j = tid; j < 2048; j += 256) kt[j] = sp2[j].x;
    __syncthreads();

    for (int idx = tid; idx < 4096; idx += 256) {
        const int c = idx >> 6, u = idx & 63;
        const int base = c * 32;
        float s = 0.f;
#pragma unroll 4
        for (int j = 0; j < 32; ++j) s += Gs[kt[base + j] * 64 + u];
        P[c][u] = s;
    }
    __syncthreads();
    if (tid < 64) {
        float acc = 0.f;
        for (int c = 0; c < 64; ++c) { float p = P[c][tid]; P[c][tid] = acc; acc += p; }
    }
    __syncthreads();
    for (int t = tid; t < NSTEP; t += 256) {
        const int c = t >> 5, base = c << 5;
        const int ktt = kt[t];
        float a = P[c][ktt];
        for (int s = base; s < t; ++s) a += Gs[kt[s] * 64 + ktt];
        Aa[t] = a;
        Ws[t] = 2.f * a + Gs[ktt * 65];
    }
    __syncthreads();
    float loc[8], tot = 0.f;
    const int base8 = tid * 8;
#pragma unroll
    for (int j = 0; j < 8; ++j) {
        float v = (base8 + j < NSTEP) ? Ws[base8 + j] : 0.f;
        loc[j] = tot; tot += v;
    }
    red[tid] = tot;
    __syncthreads();
    float run = tot;
    for (int off = 1; off < 256; off <<= 1) {
        float add = (tid >= off) ? red[tid - off] : 0.f;
        __syncthreads();
        run += add; red[tid] = run;
        __syncthreads();
    }
    const float excl = run - tot;
    __syncthreads();
#pragma unroll
    for (int j = 0; j < 8; ++j) {
        const int t = base8 + j;
        if (t < NSTEP) {
            const float u_t = excl + loc[j];
            const float tf = (float)t;
            const int ktt = kt[t];
            const float r = fmaf(tf * tf, Gs[ktt * 65] - 16.f, u_t)
                            - 2.f * tf * Aa[t];
            Ws[t] = (t == 0 || r > 0.f) ? 1.f : 0.f;
        }
    }
    __syncthreads();
    int cnt = 0;
    if (tid < 64) {
        unsigned int w = 0;
        for (int j = 0; j < 32; ++j) {
            const int t = tid * 32 + j;
            if (t < NSTEP && Ws[t] != 0.f) w |= 1u << j;
        }
        flags[b * 64 + tid] = w;
        cnt = __popc(w);
    }
    red[tid] = (float)cnt;
    __syncthreads();
    if (tid == 0) {
        float s = 0.f;
        for (int j = 0; j < 64; ++j) s += red[j];
        atomicAdd(wacc, s);
    }
}

// ---------------------------------------------------------------------------
// Phase B2: fast-weight scan. One wave per batch row, 256 blocks (1/CU).
// 2048 steps (step 2047 is a provable no-op: its flag bit is 0), structured
// as outer 64 chunks x fully-unrolled inner 32 -> compile-time readlane
// indices, SALU flag extraction, no per-step loop overhead.
// ---------------------------------------------------------------------------
__global__ __launch_bounds__(64) void scan_kernel(
    const int* __restrict__ seq, const float* __restrict__ tableg,
    const float* __restrict__ Gg, const float* __restrict__ Z0g,
    const float* __restrict__ fc1_b, const float* __restrict__ fc2_w,
    const float* __restrict__ fc2_b, const float* __restrict__ out_w,
    const float* __restrict__ out_b, const unsigned int* __restrict__ flags,
    const float* __restrict__ wacc, float* __restrict__ out)
{
    __shared__ float Gs[4096];
    __shared__ float tabs[2048];
    __shared__ float ctx_s[32];
    const int b = blockIdx.x, tid = threadIdx.x;
    const int i = tid & 7, g = tid >> 3;
    const int l31 = tid & 31;
    const int i4 = i << 2;

    // merged finalize: wacc complete (flags kernel is stream-ordered earlier)
    if (b == 0 && tid == 0) out[16384] = wacc[0] * (1.0f / 524032.0f);

    for (int idx = tid; idx < 4096; idx += 64) Gs[idx] = Gg[idx];
    for (int idx = tid; idx < 2048; idx += 64) tabs[idx] = tableg[idx];
    __syncthreads();
    const float4* tab4 = reinterpret_cast<const float4*>(tabs);

    // --- state ---
    float Zr[8];
#pragma unroll
    for (int r = 0; r < 8; ++r) Zr[r] = Z0g[(8 * g + r) * 8 + i];
    float b1 = fc1_b[i];
    float W2r0 = fc2_w[(4 * g + 0) * 8 + i];
    float W2r1 = fc2_w[(4 * g + 1) * 8 + i];
    float W2r2 = fc2_w[(4 * g + 2) * 8 + i];
    float W2r3 = fc2_w[(4 * g + 3) * 8 + i];
    float4 b2r = reinterpret_cast<const float4*>(fc2_b)[g];

    const int2* sp2 = reinterpret_cast<const int2*>(seq + b * L_SEQ);
    const unsigned int fwv = flags[b * 64 + tid];   // lane l holds flag word l

    int2 cbA = sp2[l31];          // chunk 0
    int2 cbB = sp2[32 + l31];     // chunk 1
    int2 cbC = sp2[64 + l31];     // chunk 2

    int k0t = rli(cbA.x, 0);
    int v0t = rli(cbA.y, 0);
    int kn1 = rli(cbA.x, 1);
    int vn1 = rli(cbA.y, 1);

    // --- prologue (one-time latency) ---
    const float4* gp0 = reinterpret_cast<const float4*>(Gs + k0t * 64 + 8 * g);
    float4 GaC = gp0[0], GbC = gp0[1];
    float4 vc0 = tab4[v0t * 8 + g];
    float gbIn = Gs[k0t * 64 + kn1];                 // G[k0][k1]
    float yb = bperm_row(k0t, i4, sel8u(Zr, k0t & 7)) + b1;
    float es0 = b2r.x - vc0.x, es1 = b2r.y - vc0.y;
    float es2 = b2r.z - vc0.z, es3 = b2r.w - vc0.w;
    float c_prev = 0.f, gB1c = 0.f;

    for (int c = 0; c < 64; ++c) {
        const unsigned int fw = (unsigned int)rli((int)fwv, c);
        {   // prefetch chunk c+2 tokens (1 global load / 32 steps)
            int c2 = c + 2; if (c2 > 63) c2 = 63;
            int2 t2 = sp2[c2 * 32 + l31];
            // consume below via rotation at chunk end
            cbC = t2;
        }
#pragma unroll
        for (int j = 0; j < 32; ++j) {
            // tokens for step t+2 — compile-time lane indices
            int kn2, vn2;
            if (j < 30) { kn2 = rli(cbA.x, j + 2); vn2 = rli(cbA.y, j + 2); }
            else        { kn2 = rli(cbB.x, j - 30); vn2 = rli(cbB.y, j - 30); }
            const float st = ((fw >> j) & 1u) ? ST_W : 0.f;   // uniform SALU

            // bperm for step t+1 (reads Z_{t-1}; corrected via gB1c next step)
            float ynv = bperm_row(kn1, i4, sel8u(Zr, kn1 & 7));

            // DS prefetch (depth 1): rows for step t+1
            const float4* gpn =
                reinterpret_cast<const float4*>(Gs + kn1 * 64 + 8 * g);
            float4 GaN = gpn[0], GbN = gpn[1];
            float4 vcN = tab4[vn1 * 8 + g];
            float gbNew = Gs[kn1 * 64 + kn2];        // G[k_{t+1}][k_{t+2}]

            // --- critical path (step t) ---
            const float z1 = fmaf(c_prev, gB1c, yb);
            const float a  = fmaxf(z1, 0.f);
            float p0 = W2r0 * a, p1 = W2r1 * a, p2 = W2r2 * a, p3 = W2r3 * a;
            redi4(p0, p1, p2, p3);
            const float dp0 = p0 + es0, dp1 = p1 + es1;
            const float dp2 = p2 + es2, dp3 = p3 + es3;
            float q = redg1(fmaf(W2r0, dp0, W2r1 * dp1) +
                            fmaf(W2r2, dp2, W2r3 * dp3));
            const float cc = (z1 > 0.f) ? st * q : 0.f;

            // --- updates (off critical path) ---
            const float u0 = st * dp0, u1 = st * dp1;
            const float u2 = st * dp2, u3 = st * dp3;
            W2r0 = fmaf(u0, a, W2r0); W2r1 = fmaf(u1, a, W2r1);
            W2r2 = fmaf(u2, a, W2r2); W2r3 = fmaf(u3, a, W2r3);
            b2r.x += u0; b2r.y += u1; b2r.z += u2; b2r.w += u3;
            Zr[0] = fmaf(cc, GaC.x, Zr[0]); Zr[1] = fmaf(cc, GaC.y, Zr[1]);
            Zr[2] = fmaf(cc, GaC.z, Zr[2]); Zr[3] = fmaf(cc, GaC.w, Zr[3]);
            Zr[4] = fmaf(cc, GbC.x, Zr[4]); Zr[5] = fmaf(cc, GbC.y, Zr[5]);
            Zr[6] = fmaf(cc, GbC.z, Zr[6]); Zr[7] = fmaf(cc, GbC.w, Zr[7]);
            const float ybN = ynv + b1;              // pre-update b1
            b1 += cc;
            es0 = b2r.x - vcN.x; es1 = b2r.y - vcN.y;   // es for step t+1
            es2 = b2r.z - vcN.z; es3 = b2r.w - vcN.w;

            // --- rotate (renamed by unroll) ---
            yb = ybN; c_prev = cc; gB1c = gbIn + 1.f; gbIn = gbNew;
            GaC = GaN; GbC = GbN;
            kn1 = kn2; vn1 = vn2;
        }
        cbA = cbB; cbB = cbC;
    }

    // --- query/context (state = after 2047 real steps; step 2047 was no-op) ---
    const int tq = seq[b * L_SEQ + (L_SEQ - 1)];
    float yq = bperm_row(tq, i4, sel8u(Zr, tq & 7));
    const float zq = yq + b1;
    const float aq = fmaxf(zq, 0.f);
    float c0 = W2r0 * aq, c1 = W2r1 * aq, c2 = W2r2 * aq, c3 = W2r3 * aq;
    redi4(c0, c1, c2, c3);
    if (i == 0) {
        ctx_s[4 * g + 0] = c0 + b2r.x;
        ctx_s[4 * g + 1] = c1 + b2r.y;
        ctx_s[4 * g + 2] = c2 + b2r.z;
        ctx_s[4 * g + 3] = c3 + b2r.w;
    }
    __syncthreads();

    float acc = out_b[tid];
#pragma unroll
    for (int j = 0; j < 32; ++j) acc += ctx_s[j] * out_w[tid * 32 + j];
    out[b * 64 + tid] = acc;
}

// ---------------------------------------------------------------------------
extern "C" void kernel_launch(void* const* d_in, const int* in_sizes, int n_in,
                              void* d_out, int out_size, void* d_ws, size_t ws_size,
                              hipStream_t stream)
{
    const int*   seq   = (const int*)  d_in[0];
    const float* embed = (const float*)d_in[1];
    const float* ff1_w = (const float*)d_in[2];
    const float* ff1_b = (const float*)d_in[3];
    const float* ff2_w = (const float*)d_in[4];
    const float* ff2_b = (const float*)d_in[5];
    const float* ln_g  = (const float*)d_in[6];
    const float* ln_b  = (const float*)d_in[7];
    const float* fc1_w = (const float*)d_in[8];
    const float* fc1_b = (const float*)d_in[9];
    const float* fc2_w = (const float*)d_in[10];
    const float* fc2_b = (const float*)d_in[11];
    const float* out_w = (const float*)d_in[12];
    const float* out_b = (const float*)d_in[13];

    float* out = (float*)d_out;
    char* ws = (char*)d_ws;
    float*        table = (float*)(ws + 0);
    float*        G     = (float*)(ws + 8192);
    float*        Z0    = (float*)(ws + 24576);
    float*        wacc  = (float*)(ws + 26624);
    unsigned int* flags = (unsigned int*)(ws + 28672);

    hipMemsetAsync(wacc, 0, sizeof(float), stream);
    hipLaunchKernelGGL(build_kernel, dim3(1), dim3(64), 0, stream,
                       embed, ff1_w, ff1_b, ff2_w, ff2_b, ln_g, ln_b, fc1_w,
                       table, G, Z0);
    hipLaunchKernelGGL(flags_kernel, dim3(256), dim3(256), 0, stream,
                       seq, G, flags, wacc);
    hipLaunchKernelGGL(scan_kernel, dim3(256), dim3(64), 0, stream,
                       seq, table, G, Z0, fc1_b, fc2_w, fc2_b,
                       out_w, out_b, flags, wacc, out);
}

// Round 11
// 465.470 us; speedup vs baseline: 2.6130x; 1.0146x over previous
//
#include <hip/hip_runtime.h>

#define L_SEQ 4096
#define NSTEP 2047
#define ST_W  (-0.000625f)   // -LR * (2/H) = -0.01/16

// ws layout (bytes):
//  [0,      8192)   table  64x32 f32
//  [8192,  24576)   G      64x64 f32
//  [24576, 26624)   Z0     64x8  f32
//  [26624, 26628)   wacc   f32
//  [28672, 94208)   flags  256 rows x 64 words (bit j of word c = wr_{32c+j})

// ---------------------------------------------------------------------------
// Cross-lane reduction helpers (VALU pipe). Layout: i = lane&7, g = lane>>3.
// ---------------------------------------------------------------------------
__device__ __forceinline__ void redi4(float& a, float& b, float& c, float& d) {
    asm volatile(
        "s_nop 1\n\t"
        "v_add_f32_dpp %0, %0, %0 quad_perm:[1,0,3,2] row_mask:0xf bank_mask:0xf bound_ctrl:0\n\t"
        "v_add_f32_dpp %1, %1, %1 quad_perm:[1,0,3,2] row_mask:0xf bank_mask:0xf bound_ctrl:0\n\t"
        "v_add_f32_dpp %2, %2, %2 quad_perm:[1,0,3,2] row_mask:0xf bank_mask:0xf bound_ctrl:0\n\t"
        "v_add_f32_dpp %3, %3, %3 quad_perm:[1,0,3,2] row_mask:0xf bank_mask:0xf bound_ctrl:0\n\t"
        "v_add_f32_dpp %0, %0, %0 quad_perm:[2,3,0,1] row_mask:0xf bank_mask:0xf bound_ctrl:0\n\t"
        "v_add_f32_dpp %1, %1, %1 quad_perm:[2,3,0,1] row_mask:0xf bank_mask:0xf bound_ctrl:0\n\t"
        "v_add_f32_dpp %2, %2, %2 quad_perm:[2,3,0,1] row_mask:0xf bank_mask:0xf bound_ctrl:0\n\t"
        "v_add_f32_dpp %3, %3, %3 quad_perm:[2,3,0,1] row_mask:0xf bank_mask:0xf bound_ctrl:0\n\t"
        "v_add_f32_dpp %0, %0, %0 row_half_mirror row_mask:0xf bank_mask:0xf bound_ctrl:0\n\t"
        "v_add_f32_dpp %1, %1, %1 row_half_mirror row_mask:0xf bank_mask:0xf bound_ctrl:0\n\t"
        "v_add_f32_dpp %2, %2, %2 row_half_mirror row_mask:0xf bank_mask:0xf bound_ctrl:0\n\t"
        "v_add_f32_dpp %3, %3, %3 row_half_mirror row_mask:0xf bank_mask:0xf bound_ctrl:0"
        : "+v"(a), "+v"(b), "+v"(c), "+v"(d));
}

__device__ __forceinline__ float redg1(float x) {
    float t;
    asm volatile(
        "s_nop 1\n\t"
        "v_add_f32_dpp %0, %0, %0 row_ror:8 row_mask:0xf bank_mask:0xf bound_ctrl:0\n\t"
        "s_nop 1\n\t"
        "v_mov_b32 %1, %0\n\t"
        "s_nop 1\n\t"
        "v_permlane16_swap_b32 %1, %0\n\t"
        "s_nop 0\n\t"
        "v_add_f32 %0, %0, %1\n\t"
        "s_nop 1\n\t"
        "v_mov_b32 %1, %0\n\t"
        "s_nop 1\n\t"
        "v_permlane32_swap_b32 %1, %0\n\t"
        "s_nop 0\n\t"
        "v_add_f32 %0, %0, %1"
        : "+v"(x), "=&v"(t));
    return x;
}

// select Z[r] among 8 regs; r wave-uniform (SGPR): SALU masks + 7 v_cndmask
__device__ __forceinline__ float sel8u(const float* Z, int r) {
    unsigned long long m0 = (r & 1) ? ~0ull : 0ull;
    unsigned long long m1 = (r & 2) ? ~0ull : 0ull;
    unsigned long long m2 = (r & 4) ? ~0ull : 0ull;
    float a0, a1, a2, a3, b0, b1v, res;
    asm("v_cndmask_b32 %0, %1, %2, %3" : "=v"(a0) : "v"(Z[0]), "v"(Z[1]), "s"(m0));
    asm("v_cndmask_b32 %0, %1, %2, %3" : "=v"(a1) : "v"(Z[2]), "v"(Z[3]), "s"(m0));
    asm("v_cndmask_b32 %0, %1, %2, %3" : "=v"(a2) : "v"(Z[4]), "v"(Z[5]), "s"(m0));
    asm("v_cndmask_b32 %0, %1, %2, %3" : "=v"(a3) : "v"(Z[6]), "v"(Z[7]), "s"(m0));
    asm("v_cndmask_b32 %0, %1, %2, %3" : "=v"(b0)  : "v"(a0), "v"(a1), "s"(m1));
    asm("v_cndmask_b32 %0, %1, %2, %3" : "=v"(b1v) : "v"(a2), "v"(a3), "s"(m1));
    asm("v_cndmask_b32 %0, %1, %2, %3" : "=v"(res) : "v"(b0), "v"(b1v), "s"(m2));
    return res;
}

__device__ __forceinline__ float bperm_row(int tok, int i4, float v) {
    int addr = ((tok & 56) << 2) | i4;
    return __int_as_float(__builtin_amdgcn_ds_bpermute(addr, __float_as_int(v)));
}

__device__ __forceinline__ int rli(int x, int l) {
    return __builtin_amdgcn_readlane(x, l);
}

// ---------------------------------------------------------------------------
// Phase A+B1 fused: each block builds table+G in LDS (cheap, parallel), then
// computes its row's write gates. Block 0 additionally stores table/G/Z0 to ws.
// ---------------------------------------------------------------------------
__global__ __launch_bounds__(256) void flags_kernel(
    const int* __restrict__ seq, const float* __restrict__ embed,
    const float* __restrict__ ff1_w, const float* __restrict__ ff1_b,
    const float* __restrict__ ff2_w, const float* __restrict__ ff2_b,
    const float* __restrict__ ln_g, const float* __restrict__ ln_b,
    const float* __restrict__ fc1_w,
    float* __restrict__ table, float* __restrict__ G, float* __restrict__ Z0,
    unsigned int* __restrict__ flags, float* __restrict__ wacc)
{
    __shared__ float Gs[4096];
    __shared__ float tl[64][32];
    __shared__ float P[64][64];
    __shared__ int   kt[2048];
    __shared__ float Aa[2048];
    __shared__ float Ws[2048];
    __shared__ float red[256];
    const int tid = threadIdx.x, b = blockIdx.x;
    const int2* sp2 = reinterpret_cast<const int2*>(seq + b * L_SEQ);
    for (int j = tid; j < 2048; j += 256) kt[j] = sp2[j].x;

    // --- build table rows (threads 0..63, one vocab id each) ---
    if (tid < 64) {
        const int v = tid;
        float h[32], f[32];
#pragma unroll
        for (int j = 0; j < 32; ++j) { h[j] = embed[v * 32 + j]; f[j] = 0.f; }
        for (int k = 0; k < 64; ++k) {
            float z = ff1_b[k];
#pragma unroll
            for (int j = 0; j < 32; ++j) z += h[j] * ff1_w[k * 32 + j];
            z = fmaxf(z, 0.f);
#pragma unroll
            for (int j = 0; j < 32; ++j) f[j] += z * ff2_w[j * 64 + k];
        }
        float x[32], mu = 0.f;
#pragma unroll
        for (int j = 0; j < 32; ++j) { x[j] = h[j] + f[j] + ff2_b[j]; mu += x[j]; }
        mu *= (1.f / 32.f);
        float var = 0.f;
#pragma unroll
        for (int j = 0; j < 32; ++j) { float d = x[j] - mu; var += d * d; }
        var *= (1.f / 32.f);
        const float inv = rsqrtf(var + 1e-5f);
#pragma unroll
        for (int j = 0; j < 32; ++j) {
            float tv = ln_g[j] * (x[j] - mu) * inv + ln_b[j];
            tl[v][j] = tv;
            if (b == 0) table[v * 32 + j] = tv;
        }
    }
    __syncthreads();

    // --- Gram matrix (all 256 threads) ---
    for (int idx = tid; idx < 4096; idx += 256) {
        const int v = idx >> 6, u = idx & 63;
        float acc = 0.f;
#pragma unroll
        for (int j = 0; j < 32; ++j) acc += tl[v][j] * tl[u][j];
        Gs[idx] = acc;
        if (b == 0) G[idx] = acc;
    }
    if (b == 0) {   // Z0 for the scan kernel
        for (int idx = tid; idx < 512; idx += 256) {
            const int v = idx >> 3, i = idx & 7;
            float acc = 0.f;
#pragma unroll
            for (int j = 0; j < 32; ++j) acc += fc1_w[i * 32 + j] * tl[v][j];
            Z0[idx] = acc;
        }
    }
    __syncthreads();

    // --- gate computation (identical math to R10) ---
    for (int idx = tid; idx < 4096; idx += 256) {
        const int c = idx >> 6, u = idx & 63;
        const int base = c * 32;
        float s = 0.f;
#pragma unroll 4
        for (int j = 0; j < 32; ++j) s += Gs[kt[base + j] * 64 + u];
        P[c][u] = s;
    }
    __syncthreads();
    if (tid < 64) {
        float acc = 0.f;
        for (int c = 0; c < 64; ++c) { float p = P[c][tid]; P[c][tid] = acc; acc += p; }
    }
    __syncthreads();
    for (int t = tid; t < NSTEP; t += 256) {
        const int c = t >> 5, base = c << 5;
        const int ktt = kt[t];
        float a = P[c][ktt];
        for (int s = base; s < t; ++s) a += Gs[kt[s] * 64 + ktt];
        Aa[t] = a;
        Ws[t] = 2.f * a + Gs[ktt * 65];
    }
    __syncthreads();
    float loc[8], tot = 0.f;
    const int base8 = tid * 8;
#pragma unroll
    for (int j = 0; j < 8; ++j) {
        float v = (base8 + j < NSTEP) ? Ws[base8 + j] : 0.f;
        loc[j] = tot; tot += v;
    }
    red[tid] = tot;
    __syncthreads();
    float run = tot;
    for (int off = 1; off < 256; off <<= 1) {
        float add = (tid >= off) ? red[tid - off] : 0.f;
        __syncthreads();
        run += add; red[tid] = run;
        __syncthreads();
    }
    const float excl = run - tot;
    __syncthreads();
#pragma unroll
    for (int j = 0; j < 8; ++j) {
        const int t = base8 + j;
        if (t < NSTEP) {
            const float u_t = excl + loc[j];
            const float tf = (float)t;
            const int ktt = kt[t];
            const float r = fmaf(tf * tf, Gs[ktt * 65] - 16.f, u_t)
                            - 2.f * tf * Aa[t];
            Ws[t] = (t == 0 || r > 0.f) ? 1.f : 0.f;
        }
    }
    __syncthreads();
    int cnt = 0;
    if (tid < 64) {
        unsigned int w = 0;
        for (int j = 0; j < 32; ++j) {
            const int t = tid * 32 + j;
            if (t < NSTEP && Ws[t] != 0.f) w |= 1u << j;
        }
        flags[b * 64 + tid] = w;
        cnt = __popc(w);
    }
    red[tid] = (float)cnt;
    __syncthreads();
    if (tid == 0) {
        float s = 0.f;
        for (int j = 0; j < 64; ++j) s += red[j];
        atomicAdd(wacc, s);
    }
}

// ---------------------------------------------------------------------------
// Phase B2: fast-weight scan. One wave per batch row, 256 blocks (1/CU).
// 2048 steps (last is a flag-0 no-op), outer 64 x fully-unrolled 32.
// Depth-1 pipeline: per iter extract k/v_{t+1}, issue all DS for t+1,
// compute step t. gb=G[k_t][k_{t+1}] read when both known, used next iter.
// ---------------------------------------------------------------------------
__global__ __launch_bounds__(64) void scan_kernel(
    const int* __restrict__ seq, const float* __restrict__ tableg,
    const float* __restrict__ Gg, const float* __restrict__ Z0g,
    const float* __restrict__ fc1_b, const float* __restrict__ fc2_w,
    const float* __restrict__ fc2_b, const float* __restrict__ out_w,
    const float* __restrict__ out_b, const unsigned int* __restrict__ flags,
    const float* __restrict__ wacc, float* __restrict__ out)
{
    __shared__ float Gs[4096];
    __shared__ float tabs[2048];
    __shared__ float ctx_s[32];
    const int b = blockIdx.x, tid = threadIdx.x;
    const int i = tid & 7, g = tid >> 3;
    const int l31 = tid & 31;
    const int i4 = i << 2;

    // merged finalize (wacc complete: flags kernel stream-ordered earlier)
    if (b == 0 && tid == 0) out[16384] = wacc[0] * (1.0f / 524032.0f);

    for (int idx = tid; idx < 4096; idx += 64) Gs[idx] = Gg[idx];
    for (int idx = tid; idx < 2048; idx += 64) tabs[idx] = tableg[idx];
    __syncthreads();
    const float4* tab4 = reinterpret_cast<const float4*>(tabs);

    // --- state ---
    float Zr[8];
#pragma unroll
    for (int r = 0; r < 8; ++r) Zr[r] = Z0g[(8 * g + r) * 8 + i];
    float b1 = fc1_b[i];
    float W2r0 = fc2_w[(4 * g + 0) * 8 + i];
    float W2r1 = fc2_w[(4 * g + 1) * 8 + i];
    float W2r2 = fc2_w[(4 * g + 2) * 8 + i];
    float W2r3 = fc2_w[(4 * g + 3) * 8 + i];
    float4 b2r = reinterpret_cast<const float4*>(fc2_b)[g];

    const int2* sp2 = reinterpret_cast<const int2*>(seq + b * L_SEQ);
    const unsigned int fwv = flags[b * 64 + tid];   // lane l holds flag word l

    int2 cbA = sp2[l31];          // chunk c
    int2 cbB = sp2[32 + l31];     // chunk c+1
    int2 cbC;                     // chunk c+2 (prefetched per chunk)

    // --- prologue (t = 0) ---
    int kS = rli(cbA.x, 0);
    int vS = rli(cbA.y, 0);
    const float4* gp0 = reinterpret_cast<const float4*>(Gs + kS * 64 + 8 * g);
    float4 GaC = gp0[0], GbC = gp0[1];
    float4 vc0 = tab4[vS * 8 + g];
    float yb = bperm_row(kS, i4, sel8u(Zr, kS & 7)) + b1;
    float es0 = b2r.x - vc0.x, es1 = b2r.y - vc0.y;
    float es2 = b2r.z - vc0.z, es3 = b2r.w - vc0.w;
    float c_prev = 0.f, gB1c = 0.f;

    for (int c = 0; c < 64; ++c) {
        const unsigned int fw = (unsigned int)rli((int)fwv, c);
        {   // prefetch chunk c+2 tokens (1 global load / 32 steps)
            int c2 = c + 2; if (c2 > 63) c2 = 63;
            cbC = sp2[c2 * 32 + l31];
        }
#pragma unroll
        for (int j = 0; j < 32; ++j) {
            // token for step t+1 — compile-time lane index
            int kN, vN;
            if (j < 31) { kN = rli(cbA.x, j + 1); vN = rli(cbA.y, j + 1); }
            else        { kN = rli(cbB.x, 0);     vN = rli(cbB.y, 0); }
            const float st = ((fw >> j) & 1u) ? ST_W : 0.f;   // uniform SALU

            // issue ALL DS for step t+1 (consumed next iter; ~1 iter slack)
            float ynv = bperm_row(kN, i4, sel8u(Zr, kN & 7)); // reads Z_{t-1}
            const float4* gpn =
                reinterpret_cast<const float4*>(Gs + kN * 64 + 8 * g);
            float4 GaN = gpn[0], GbN = gpn[1];
            float4 vcN = tab4[vN * 8 + g];
            float gbN = Gs[kS * 64 + kN];        // G[k_t][k_{t+1}]

            // --- critical path (step t) ---
            const float z1 = fmaf(c_prev, gB1c, yb);
            const float a  = fmaxf(z1, 0.f);
            float p0 = W2r0 * a, p1 = W2r1 * a, p2 = W2r2 * a, p3 = W2r3 * a;
            redi4(p0, p1, p2, p3);
            const float dp0 = p0 + es0, dp1 = p1 + es1;
            const float dp2 = p2 + es2, dp3 = p3 + es3;
            float q = redg1(fmaf(W2r0, dp0, W2r1 * dp1) +
                            fmaf(W2r2, dp2, W2r3 * dp3));
            const float cc = (z1 > 0.f) ? st * q : 0.f;

            // --- updates (off critical path) ---
            const float u0 = st * dp0, u1 = st * dp1;
            const float u2 = st * dp2, u3 = st * dp3;
            W2r0 = fmaf(u0, a, W2r0); W2r1 = fmaf(u1, a, W2r1);
            W2r2 = fmaf(u2, a, W2r2); W2r3 = fmaf(u3, a, W2r3);
            b2r.x += u0; b2r.y += u1; b2r.z += u2; b2r.w += u3;
            Zr[0] = fmaf(cc, GaC.x, Zr[0]); Zr[1] = fmaf(cc, GaC.y, Zr[1]);
            Zr[2] = fmaf(cc, GaC.z, Zr[2]); Zr[3] = fmaf(cc, GaC.w, Zr[3]);
            Zr[4] = fmaf(cc, GbC.x, Zr[4]); Zr[5] = fmaf(cc, GbC.y, Zr[5]);
            Zr[6] = fmaf(cc, GbC.z, Zr[6]); Zr[7] = fmaf(cc, GbC.w, Zr[7]);
            const float ybN = ynv + b1;          // pre-update b1 (b1_{t-1})
            b1 += cc;
            es0 = b2r.x - vcN.x; es1 = b2r.y - vcN.y;   // es for step t+1
            es2 = b2r.z - vcN.z; es3 = b2r.w - vcN.w;

            // --- rotate (renamed by unroll) ---
            yb = ybN; c_prev = cc; gB1c = gbN + 1.f;
            GaC = GaN; GbC = GbN; kS = kN;
        }
        cbA = cbB; cbB = cbC;
    }

    // --- query/context (state = after the 2047 real steps) ---
    const int tq = seq[b * L_SEQ + (L_SEQ - 1)];
    float yq = bperm_row(tq, i4, sel8u(Zr, tq & 7));
    const float zq = yq + b1;
    const float aq = fmaxf(zq, 0.f);
    float c0 = W2r0 * aq, c1 = W2r1 * aq, c2 = W2r2 * aq, c3 = W2r3 * aq;
    redi4(c0, c1, c2, c3);
    if (i == 0) {
        ctx_s[4 * g + 0] = c0 + b2r.x;
        ctx_s[4 * g + 1] = c1 + b2r.y;
        ctx_s[4 * g + 2] = c2 + b2r.z;
        ctx_s[4 * g + 3] = c3 + b2r.w;
    }
    __syncthreads();

    float acc = out_b[tid];
#pragma unroll
    for (int j = 0; j < 32; ++j) acc += ctx_s[j] * out_w[tid * 32 + j];
    out[b * 64 + tid] = acc;
}

// ---------------------------------------------------------------------------
extern "C" void kernel_launch(void* const* d_in, const int* in_sizes, int n_in,
                              void* d_out, int out_size, void* d_ws, size_t ws_size,
                              hipStream_t stream)
{
    const int*   seq   = (const int*)  d_in[0];
    const float* embed = (const float*)d_in[1];
    const float* ff1_w = (const float*)d_in[2];
    const float* ff1_b = (const float*)d_in[3];
    const float* ff2_w = (const float*)d_in[4];
    const float* ff2_b = (const float*)d_in[5];
    const float* ln_g  = (const float*)d_in[6];
    const float* ln_b  = (const float*)d_in[7];
    const float* fc1_w = (const float*)d_in[8];
    const float* fc1_b = (const float*)d_in[9];
    const float* fc2_w = (const float*)d_in[10];
    const float* fc2_b = (const float*)d_in[11];
    const float* out_w = (const float*)d_in[12];
    const float* out_b = (const float*)d_in[13];

    float* out = (float*)d_out;
    char* ws = (char*)d_ws;
    float*        table = (float*)(ws + 0);
    float*        G     = (float*)(ws + 8192);
    float*        Z0    = (float*)(ws + 24576);
    float*        wacc  = (float*)(ws + 26624);
    unsigned int* flags = (unsigned int*)(ws + 28672);

    hipMemsetAsync(wacc, 0, sizeof(float), stream);
    hipLaunchKernelGGL(flags_kernel, dim3(256), dim3(256), 0, stream,
                       seq, embed, ff1_w, ff1_b, ff2_w, ff2_b, ln_g, ln_b,
                       fc1_w, table, G, Z0, flags, wacc);
    hipLaunchKernelGGL(scan_kernel, dim3(256), dim3(64), 0, stream,
                       seq, table, G, Z0, fc1_b, fc2_w, fc2_b,
                       out_w, out_b, flags, wacc, out);
}

// Round 12
// 460.118 us; speedup vs baseline: 2.6434x; 1.0116x over previous
//
#include <hip/hip_runtime.h>

#define L_SEQ 4096
#define NSTEP 2047
#define ST_W  (-0.000625f)   // -LR * (2/H) = -0.01/16

typedef float f32x4 __attribute__((ext_vector_type(4)));

// ws layout (bytes):
//  [0,      8192)   table  64x32 f32
//  [8192,  24576)   G      64x64 f32
//  [24576, 26624)   Z0     64x8  f32
//  [26624, 26628)   wacc   f32
//  [28672, 94208)   flags  256 rows x 64 words (bit j of word c = wr_{32c+j})

// ---------------------------------------------------------------------------
// Cross-lane reduction helpers (VALU pipe). Layout: i = lane&7, g = lane>>3.
// ---------------------------------------------------------------------------
__device__ __forceinline__ void redi4(float& a, float& b, float& c, float& d) {
    asm volatile(
        "s_nop 1\n\t"
        "v_add_f32_dpp %0, %0, %0 quad_perm:[1,0,3,2] row_mask:0xf bank_mask:0xf bound_ctrl:0\n\t"
        "v_add_f32_dpp %1, %1, %1 quad_perm:[1,0,3,2] row_mask:0xf bank_mask:0xf bound_ctrl:0\n\t"
        "v_add_f32_dpp %2, %2, %2 quad_perm:[1,0,3,2] row_mask:0xf bank_mask:0xf bound_ctrl:0\n\t"
        "v_add_f32_dpp %3, %3, %3 quad_perm:[1,0,3,2] row_mask:0xf bank_mask:0xf bound_ctrl:0\n\t"
        "v_add_f32_dpp %0, %0, %0 quad_perm:[2,3,0,1] row_mask:0xf bank_mask:0xf bound_ctrl:0\n\t"
        "v_add_f32_dpp %1, %1, %1 quad_perm:[2,3,0,1] row_mask:0xf bank_mask:0xf bound_ctrl:0\n\t"
        "v_add_f32_dpp %2, %2, %2 quad_perm:[2,3,0,1] row_mask:0xf bank_mask:0xf bound_ctrl:0\n\t"
        "v_add_f32_dpp %3, %3, %3 quad_perm:[2,3,0,1] row_mask:0xf bank_mask:0xf bound_ctrl:0\n\t"
        "v_add_f32_dpp %0, %0, %0 row_half_mirror row_mask:0xf bank_mask:0xf bound_ctrl:0\n\t"
        "v_add_f32_dpp %1, %1, %1 row_half_mirror row_mask:0xf bank_mask:0xf bound_ctrl:0\n\t"
        "v_add_f32_dpp %2, %2, %2 row_half_mirror row_mask:0xf bank_mask:0xf bound_ctrl:0\n\t"
        "v_add_f32_dpp %3, %3, %3 row_half_mirror row_mask:0xf bank_mask:0xf bound_ctrl:0"
        : "+v"(a), "+v"(b), "+v"(c), "+v"(d));
}

__device__ __forceinline__ float redg1(float x) {
    float t;
    asm volatile(
        "s_nop 1\n\t"
        "v_add_f32_dpp %0, %0, %0 row_ror:8 row_mask:0xf bank_mask:0xf bound_ctrl:0\n\t"
        "s_nop 1\n\t"
        "v_mov_b32 %1, %0\n\t"
        "s_nop 1\n\t"
        "v_permlane16_swap_b32 %1, %0\n\t"
        "s_nop 0\n\t"
        "v_add_f32 %0, %0, %1\n\t"
        "s_nop 1\n\t"
        "v_mov_b32 %1, %0\n\t"
        "s_nop 1\n\t"
        "v_permlane32_swap_b32 %1, %0\n\t"
        "s_nop 0\n\t"
        "v_add_f32 %0, %0, %1"
        : "+v"(x), "=&v"(t));
    return x;
}

// select Z[r] among 8 regs; r wave-uniform (SGPR): SALU masks + 7 v_cndmask
__device__ __forceinline__ float sel8u(const float* Z, int r) {
    unsigned long long m0 = (r & 1) ? ~0ull : 0ull;
    unsigned long long m1 = (r & 2) ? ~0ull : 0ull;
    unsigned long long m2 = (r & 4) ? ~0ull : 0ull;
    float a0, a1, a2, a3, b0, b1v, res;
    asm("v_cndmask_b32 %0, %1, %2, %3" : "=v"(a0) : "v"(Z[0]), "v"(Z[1]), "s"(m0));
    asm("v_cndmask_b32 %0, %1, %2, %3" : "=v"(a1) : "v"(Z[2]), "v"(Z[3]), "s"(m0));
    asm("v_cndmask_b32 %0, %1, %2, %3" : "=v"(a2) : "v"(Z[4]), "v"(Z[5]), "s"(m0));
    asm("v_cndmask_b32 %0, %1, %2, %3" : "=v"(a3) : "v"(Z[6]), "v"(Z[7]), "s"(m0));
    asm("v_cndmask_b32 %0, %1, %2, %3" : "=v"(b0)  : "v"(a0), "v"(a1), "s"(m1));
    asm("v_cndmask_b32 %0, %1, %2, %3" : "=v"(b1v) : "v"(a2), "v"(a3), "s"(m1));
    asm("v_cndmask_b32 %0, %1, %2, %3" : "=v"(res) : "v"(b0), "v"(b1v), "s"(m2));
    return res;
}

__device__ __forceinline__ float bperm_row(int tok, int i4, float v) {
    int addr = ((tok & 56) << 2) | i4;
    return __int_as_float(__builtin_amdgcn_ds_bpermute(addr, __float_as_int(v)));
}

__device__ __forceinline__ int rli(int x, int l) {
    return __builtin_amdgcn_readlane(x, l);
}

// ---------------------------------------------------------------------------
// Phase A+B1 fused: each block builds table+G in LDS, then its row's gates.
// Block 0 additionally stores table/G/Z0 to ws for the scan kernel.
// ---------------------------------------------------------------------------
__global__ __launch_bounds__(256) void flags_kernel(
    const int* __restrict__ seq, const float* __restrict__ embed,
    const float* __restrict__ ff1_w, const float* __restrict__ ff1_b,
    const float* __restrict__ ff2_w, const float* __restrict__ ff2_b,
    const float* __restrict__ ln_g, const float* __restrict__ ln_b,
    const float* __restrict__ fc1_w,
    float* __restrict__ table, float* __restrict__ G, float* __restrict__ Z0,
    unsigned int* __restrict__ flags, float* __restrict__ wacc)
{
    __shared__ float Gs[4096];
    __shared__ float tl[64][32];
    __shared__ float P[64][64];
    __shared__ int   kt[2048];
    __shared__ float Aa[2048];
    __shared__ float Ws[2048];
    __shared__ float red[256];
    const int tid = threadIdx.x, b = blockIdx.x;
    const int2* sp2 = reinterpret_cast<const int2*>(seq + b * L_SEQ);
    for (int j = tid; j < 2048; j += 256) kt[j] = sp2[j].x;

    if (tid < 64) {
        const int v = tid;
        float h[32], f[32];
#pragma unroll
        for (int j = 0; j < 32; ++j) { h[j] = embed[v * 32 + j]; f[j] = 0.f; }
        for (int k = 0; k < 64; ++k) {
            float z = ff1_b[k];
#pragma unroll
            for (int j = 0; j < 32; ++j) z += h[j] * ff1_w[k * 32 + j];
            z = fmaxf(z, 0.f);
#pragma unroll
            for (int j = 0; j < 32; ++j) f[j] += z * ff2_w[j * 64 + k];
        }
        float x[32], mu = 0.f;
#pragma unroll
        for (int j = 0; j < 32; ++j) { x[j] = h[j] + f[j] + ff2_b[j]; mu += x[j]; }
        mu *= (1.f / 32.f);
        float var = 0.f;
#pragma unroll
        for (int j = 0; j < 32; ++j) { float d = x[j] - mu; var += d * d; }
        var *= (1.f / 32.f);
        const float inv = rsqrtf(var + 1e-5f);
#pragma unroll
        for (int j = 0; j < 32; ++j) {
            float tv = ln_g[j] * (x[j] - mu) * inv + ln_b[j];
            tl[v][j] = tv;
            if (b == 0) table[v * 32 + j] = tv;
        }
    }
    __syncthreads();

    for (int idx = tid; idx < 4096; idx += 256) {
        const int v = idx >> 6, u = idx & 63;
        float acc = 0.f;
#pragma unroll
        for (int j = 0; j < 32; ++j) acc += tl[v][j] * tl[u][j];
        Gs[idx] = acc;
        if (b == 0) G[idx] = acc;
    }
    if (b == 0) {
        for (int idx = tid; idx < 512; idx += 256) {
            const int v = idx >> 3, i = idx & 7;
            float acc = 0.f;
#pragma unroll
            for (int j = 0; j < 32; ++j) acc += fc1_w[i * 32 + j] * tl[v][j];
            Z0[idx] = acc;
        }
    }
    __syncthreads();

    for (int idx = tid; idx < 4096; idx += 256) {
        const int c = idx >> 6, u = idx & 63;
        const int base = c * 32;
        float s = 0.f;
#pragma unroll 4
        for (int j = 0; j < 32; ++j) s += Gs[kt[base + j] * 64 + u];
        P[c][u] = s;
    }
    __syncthreads();
    if (tid < 64) {
        float acc = 0.f;
        for (int c = 0; c < 64; ++c) { float p = P[c][tid]; P[c][tid] = acc; acc += p; }
    }
    __syncthreads();
    for (int t = tid; t < NSTEP; t += 256) {
        const int c = t >> 5, base = c << 5;
        const int ktt = kt[t];
        float a = P[c][ktt];
        for (int s = base; s < t; ++s) a += Gs[kt[s] * 64 + ktt];
        Aa[t] = a;
        Ws[t] = 2.f * a + Gs[ktt * 65];
    }
    __syncthreads();
    float loc[8], tot = 0.f;
    const int base8 = tid * 8;
#pragma unroll
    for (int j = 0; j < 8; ++j) {
        float v = (base8 + j < NSTEP) ? Ws[base8 + j] : 0.f;
        loc[j] = tot; tot += v;
    }
    red[tid] = tot;
    __syncthreads();
    float run = tot;
    for (int off = 1; off < 256; off <<= 1) {
        float add = (tid >= off) ? red[tid - off] : 0.f;
        __syncthreads();
        run += add; red[tid] = run;
        __syncthreads();
    }
    const float excl = run - tot;
    __syncthreads();
#pragma unroll
    for (int j = 0; j < 8; ++j) {
        const int t = base8 + j;
        if (t < NSTEP) {
            const float u_t = excl + loc[j];
            const float tf = (float)t;
            const int ktt = kt[t];
            const float r = fmaf(tf * tf, Gs[ktt * 65] - 16.f, u_t)
                            - 2.f * tf * Aa[t];
            Ws[t] = (t == 0 || r > 0.f) ? 1.f : 0.f;
        }
    }
    __syncthreads();
    int cnt = 0;
    if (tid < 64) {
        unsigned int w = 0;
        for (int j = 0; j < 32; ++j) {
            const int t = tid * 32 + j;
            if (t < NSTEP && Ws[t] != 0.f) w |= 1u << j;
        }
        flags[b * 64 + tid] = w;
        cnt = __popc(w);
    }
    red[tid] = (float)cnt;
    __syncthreads();
    if (tid == 0) {
        float s = 0.f;
        for (int j = 0; j < 64; ++j) s += red[j];
        atomicAdd(wacc, s);
    }
}

// ---------------------------------------------------------------------------
// Phase B2: fast-weight scan. One wave per batch row, 256 blocks (1/CU).
// Hand-scheduled DS: all 5 LDS ops issued in one asm block at step TOP;
// single counted s_waitcnt lgkmcnt(0) at step BOTTOM ("+v" data-flow so
// consumers cannot hoist above it). Full step of slack >= LDS latency.
// ---------------------------------------------------------------------------
__global__ __launch_bounds__(64) void scan_kernel(
    const int* __restrict__ seq, const float* __restrict__ tableg,
    const float* __restrict__ Gg, const float* __restrict__ Z0g,
    const float* __restrict__ fc1_b, const float* __restrict__ fc2_w,
    const float* __restrict__ fc2_b, const float* __restrict__ out_w,
    const float* __restrict__ out_b, const unsigned int* __restrict__ flags,
    const float* __restrict__ wacc, float* __restrict__ out)
{
    __shared__ float Gs[4096];
    __shared__ float tabs[2048];
    __shared__ float ctx_s[32];
    const int b = blockIdx.x, tid = threadIdx.x;
    const int i = tid & 7, g = tid >> 3;
    const int l31 = tid & 31;
    const int i4 = i << 2;

    if (b == 0 && tid == 0) out[16384] = wacc[0] * (1.0f / 524032.0f);

    for (int idx = tid; idx < 4096; idx += 64) Gs[idx] = Gg[idx];
    for (int idx = tid; idx < 2048; idx += 64) tabs[idx] = tableg[idx];
    __syncthreads();
    const f32x4* tab4 = reinterpret_cast<const f32x4*>(tabs);

    // --- state ---
    float Zr[8];
#pragma unroll
    for (int r = 0; r < 8; ++r) Zr[r] = Z0g[(8 * g + r) * 8 + i];
    float b1 = fc1_b[i];
    float W2r0 = fc2_w[(4 * g + 0) * 8 + i];
    float W2r1 = fc2_w[(4 * g + 1) * 8 + i];
    float W2r2 = fc2_w[(4 * g + 2) * 8 + i];
    float W2r3 = fc2_w[(4 * g + 3) * 8 + i];
    f32x4 b2r = *reinterpret_cast<const f32x4*>(fc2_b + 4 * g);

    const int2* sp2 = reinterpret_cast<const int2*>(seq + b * L_SEQ);
    const unsigned int fwv = flags[b * 64 + tid];   // lane l holds flag word l

    int2 cbA = sp2[l31];          // chunk c
    int2 cbB = sp2[32 + l31];     // chunk c+1
    int2 cbC;                     // chunk c+2 (prefetched per chunk)

    // --- prologue (t = 0) ---
    int kS = rli(cbA.x, 0);
    int vS = rli(cbA.y, 0);
    const f32x4* gp0 = reinterpret_cast<const f32x4*>(Gs + kS * 64 + 8 * g);
    f32x4 GaC = gp0[0], GbC = gp0[1];
    f32x4 vc0 = tab4[vS * 8 + g];
    float yb = bperm_row(kS, i4, sel8u(Zr, kS & 7)) + b1;
    float es0 = b2r.x - vc0.x, es1 = b2r.y - vc0.y;
    float es2 = b2r.z - vc0.z, es3 = b2r.w - vc0.w;
    float c_prev = 0.f, gB1c = 0.f;

    for (int c = 0; c < 64; ++c) {
        const unsigned int fw = (unsigned int)rli((int)fwv, c);
        {   // prefetch chunk c+2 tokens (1 global load / 32 steps, vmcnt)
            int c2 = c + 2; if (c2 > 63) c2 = 63;
            cbC = sp2[c2 * 32 + l31];
        }
#pragma unroll
        for (int j = 0; j < 32; ++j) {
            // token for step t+1 — compile-time lane index
            int kN, vN;
            if (j < 31) { kN = rli(cbA.x, j + 1); vN = rli(cbA.y, j + 1); }
            else        { kN = rli(cbB.x, 0);     vN = rli(cbB.y, 0); }
            const float st = ((fw >> j) & 1u) ? ST_W : 0.f;

            // --- asm block A: issue ALL DS for step t+1 at the top ---
            const float zsel = sel8u(Zr, kN & 7);            // reads Z_{t-1}
            const int aBp = ((kN & 56) << 2) | i4;
            const unsigned aGa = (unsigned)(uintptr_t)(Gs + kN * 64 + 8 * g);
            const unsigned aVc = (unsigned)(uintptr_t)(tabs + vN * 32 + 4 * g);
            const unsigned aGb = (unsigned)(uintptr_t)(Gs + kS * 64 + kN);
            f32x4 GaN, GbN, vcN; float gbN, ynv;
            asm volatile(
                "s_nop 1\n\t"
                "ds_bpermute_b32 %4, %5, %6\n\t"
                "ds_read_b128 %0, %7\n\t"
                "ds_read_b128 %1, %7 offset:16\n\t"
                "ds_read_b128 %2, %8\n\t"
                "ds_read_b32 %3, %9"
                : "=&v"(GaN), "=&v"(GbN), "=&v"(vcN), "=&v"(gbN), "=&v"(ynv)
                : "v"(aBp), "v"(zsel), "v"(aGa), "v"(aVc), "v"(aGb));

            // --- critical path (step t) — runs while DS are in flight ---
            const float z1 = fmaf(c_prev, gB1c, yb);
            const float a  = fmaxf(z1, 0.f);
            float p0 = W2r0 * a, p1 = W2r1 * a, p2 = W2r2 * a, p3 = W2r3 * a;
            redi4(p0, p1, p2, p3);
            const float dp0 = p0 + es0, dp1 = p1 + es1;
            const float dp2 = p2 + es2, dp3 = p3 + es3;
            float q = redg1(fmaf(W2r0, dp0, W2r1 * dp1) +
                            fmaf(W2r2, dp2, W2r3 * dp3));
            const float cc = (z1 > 0.f) ? st * q : 0.f;

            // --- updates (still DS-independent) ---
            const float u0 = st * dp0, u1 = st * dp1;
            const float u2 = st * dp2, u3 = st * dp3;
            W2r0 = fmaf(u0, a, W2r0); W2r1 = fmaf(u1, a, W2r1);
            W2r2 = fmaf(u2, a, W2r2); W2r3 = fmaf(u3, a, W2r3);
            b2r.x += u0; b2r.y += u1; b2r.z += u2; b2r.w += u3;
            Zr[0] = fmaf(cc, GaC.x, Zr[0]); Zr[1] = fmaf(cc, GaC.y, Zr[1]);
            Zr[2] = fmaf(cc, GaC.z, Zr[2]); Zr[3] = fmaf(cc, GaC.w, Zr[3]);
            Zr[4] = fmaf(cc, GbC.x, Zr[4]); Zr[5] = fmaf(cc, GbC.y, Zr[5]);
            Zr[6] = fmaf(cc, GbC.z, Zr[6]); Zr[7] = fmaf(cc, GbC.w, Zr[7]);
            const float b1pre = b1;
            b1 += cc;

            // --- asm block B: single counted wait, latest possible point ---
            asm volatile("s_waitcnt lgkmcnt(0)"
                : "+v"(GaN), "+v"(GbN), "+v"(vcN), "+v"(gbN), "+v"(ynv));

            // --- consume DS results + rotate ---
            yb = ynv + b1pre;              // uses pre-update b1
            gB1c = gbN + 1.f;
            es0 = b2r.x - vcN.x; es1 = b2r.y - vcN.y;
            es2 = b2r.z - vcN.z; es3 = b2r.w - vcN.w;
            c_prev = cc;
            GaC = GaN; GbC = GbN;
            kS = kN;
        }
        cbA = cbB; cbB = cbC;
    }

    // --- query/context (state = after the 2047 real steps) ---
    const int tq = seq[b * L_SEQ + (L_SEQ - 1)];
    float yq = bperm_row(tq, i4, sel8u(Zr, tq & 7));
    const float zq = yq + b1;
    const float aq = fmaxf(zq, 0.f);
    float c0 = W2r0 * aq, c1 = W2r1 * aq, c2 = W2r2 * aq, c3 = W2r3 * aq;
    redi4(c0, c1, c2, c3);
    if (i == 0) {
        ctx_s[4 * g + 0] = c0 + b2r.x;
        ctx_s[4 * g + 1] = c1 + b2r.y;
        ctx_s[4 * g + 2] = c2 + b2r.z;
        ctx_s[4 * g + 3] = c3 + b2r.w;
    }
    __syncthreads();

    float acc = out_b[tid];
#pragma unroll
    for (int j = 0; j < 32; ++j) acc += ctx_s[j] * out_w[tid * 32 + j];
    out[b * 64 + tid] = acc;
}

// ---------------------------------------------------------------------------
extern "C" void kernel_launch(void* const* d_in, const int* in_sizes, int n_in,
                              void* d_out, int out_size, void* d_ws, size_t ws_size,
                              hipStream_t stream)
{
    const int*   seq   = (const int*)  d_in[0];
    const float* embed = (const float*)d_in[1];
    const float* ff1_w = (const float*)d_in[2];
    const float* ff1_b = (const float*)d_in[3];
    const float* ff2_w = (const float*)d_in[4];
    const float* ff2_b = (const float*)d_in[5];
    const float* ln_g  = (const float*)d_in[6];
    const float* ln_b  = (const float*)d_in[7];
    const float* fc1_w = (const float*)d_in[8];
    const float* fc1_b = (const float*)d_in[9];
    const float* fc2_w = (const float*)d_in[10];
    const float* fc2_b = (const float*)d_in[11];
    const float* out_w = (const float*)d_in[12];
    const float* out_b = (const float*)d_in[13];

    float* out = (float*)d_out;
    char* ws = (char*)d_ws;
    float*        table = (float*)(ws + 0);
    float*        G     = (float*)(ws + 8192);
    float*        Z0    = (float*)(ws + 24576);
    float*        wacc  = (float*)(ws + 26624);
    unsigned int* flags = (unsigned int*)(ws + 28672);

    hipMemsetAsync(wacc, 0, sizeof(float), stream);
    hipLaunchKernelGGL(flags_kernel, dim3(256), dim3(256), 0, stream,
                       seq, embed, ff1_w, ff1_b, ff2_w, ff2_b, ln_g, ln_b,
                       fc1_w, table, G, Z0, flags, wacc);
    hipLaunchKernelGGL(scan_kernel, dim3(256), dim3(64), 0, stream,
                       seq, table, G, Z0, fc1_b, fc2_w, fc2_b,
                       out_w, out_b, flags, wacc, out);
}

// Round 13
// 451.003 us; speedup vs baseline: 2.6968x; 1.0202x over previous
//
#include <hip/hip_runtime.h>

#define L_SEQ 4096
#define NSTEP 2047
#define ST_W  (-0.000625f)   // -LR * (2/H) = -0.01/16

typedef float f32x4 __attribute__((ext_vector_type(4)));

// ws layout (bytes):
//  [0,      8192)   table  64x32 f32
//  [8192,  24576)   G      64x64 f32
//  [24576, 26624)   Z0     64x8  f32
//  [26624, 26628)   wacc   f32
//  [28672, 94208)   flags  256 rows x 64 words (bit j of word c = wr_{32c+j})

// ---------------------------------------------------------------------------
// Cross-lane reduction helpers (VALU pipe). Layout: i = lane&7, g = lane>>3.
// ---------------------------------------------------------------------------
__device__ __forceinline__ void redi4(float& a, float& b, float& c, float& d) {
    asm volatile(
        "s_nop 1\n\t"
        "v_add_f32_dpp %0, %0, %0 quad_perm:[1,0,3,2] row_mask:0xf bank_mask:0xf bound_ctrl:0\n\t"
        "v_add_f32_dpp %1, %1, %1 quad_perm:[1,0,3,2] row_mask:0xf bank_mask:0xf bound_ctrl:0\n\t"
        "v_add_f32_dpp %2, %2, %2 quad_perm:[1,0,3,2] row_mask:0xf bank_mask:0xf bound_ctrl:0\n\t"
        "v_add_f32_dpp %3, %3, %3 quad_perm:[1,0,3,2] row_mask:0xf bank_mask:0xf bound_ctrl:0\n\t"
        "v_add_f32_dpp %0, %0, %0 quad_perm:[2,3,0,1] row_mask:0xf bank_mask:0xf bound_ctrl:0\n\t"
        "v_add_f32_dpp %1, %1, %1 quad_perm:[2,3,0,1] row_mask:0xf bank_mask:0xf bound_ctrl:0\n\t"
        "v_add_f32_dpp %2, %2, %2 quad_perm:[2,3,0,1] row_mask:0xf bank_mask:0xf bound_ctrl:0\n\t"
        "v_add_f32_dpp %3, %3, %3 quad_perm:[2,3,0,1] row_mask:0xf bank_mask:0xf bound_ctrl:0\n\t"
        "v_add_f32_dpp %0, %0, %0 row_half_mirror row_mask:0xf bank_mask:0xf bound_ctrl:0\n\t"
        "v_add_f32_dpp %1, %1, %1 row_half_mirror row_mask:0xf bank_mask:0xf bound_ctrl:0\n\t"
        "v_add_f32_dpp %2, %2, %2 row_half_mirror row_mask:0xf bank_mask:0xf bound_ctrl:0\n\t"
        "v_add_f32_dpp %3, %3, %3 row_half_mirror row_mask:0xf bank_mask:0xf bound_ctrl:0"
        : "+v"(a), "+v"(b), "+v"(c), "+v"(d));
}

__device__ __forceinline__ float redg1(float x) {
    float t;
    asm volatile(
        "s_nop 1\n\t"
        "v_add_f32_dpp %0, %0, %0 row_ror:8 row_mask:0xf bank_mask:0xf bound_ctrl:0\n\t"
        "v_mov_b32 %1, %0\n\t"
        "s_nop 1\n\t"
        "v_permlane16_swap_b32 %1, %0\n\t"
        "v_add_f32 %0, %0, %1\n\t"
        "v_mov_b32 %1, %0\n\t"
        "s_nop 1\n\t"
        "v_permlane32_swap_b32 %1, %0\n\t"
        "v_add_f32 %0, %0, %1"
        : "+v"(x), "=&v"(t));
    return x;
}

// select Z[r] among 8 regs; r wave-uniform (SGPR). SALU masks; ONE asm block
// with exactly 7 v_cndmask (single scheduler boundary).
__device__ __forceinline__ float sel8u(const float* Z, int r) {
    unsigned long long m0 = (r & 1) ? ~0ull : 0ull;
    unsigned long long m1 = (r & 2) ? ~0ull : 0ull;
    unsigned long long m2 = (r & 4) ? ~0ull : 0ull;
    float res, t0, t1, t2;
    asm("v_cndmask_b32 %1, %4, %5, %12\n\t"
        "v_cndmask_b32 %2, %6, %7, %12\n\t"
        "v_cndmask_b32 %3, %8, %9, %12\n\t"
        "v_cndmask_b32 %0, %10, %11, %12\n\t"
        "v_cndmask_b32 %1, %1, %2, %13\n\t"
        "v_cndmask_b32 %3, %3, %0, %13\n\t"
        "v_cndmask_b32 %0, %1, %3, %14"
        : "=&v"(res), "=&v"(t0), "=&v"(t1), "=&v"(t2)
        : "v"(Z[0]), "v"(Z[1]), "v"(Z[2]), "v"(Z[3]),
          "v"(Z[4]), "v"(Z[5]), "v"(Z[6]), "v"(Z[7]),
          "s"(m0), "s"(m1), "s"(m2));
    return res;
}

__device__ __forceinline__ float bperm_row(int tok, int i4, float v) {
    int addr = ((tok & 56) << 2) | i4;
    return __int_as_float(__builtin_amdgcn_ds_bpermute(addr, __float_as_int(v)));
}

__device__ __forceinline__ int rli(int x, int l) {
    return __builtin_amdgcn_readlane(x, l);
}

// ---------------------------------------------------------------------------
// Phase A+B1 fused: each block builds table+G in LDS, then its row's gates.
// Block 0 additionally stores table/G/Z0 to ws for the scan kernel.
// ---------------------------------------------------------------------------
__global__ __launch_bounds__(256) void flags_kernel(
    const int* __restrict__ seq, const float* __restrict__ embed,
    const float* __restrict__ ff1_w, const float* __restrict__ ff1_b,
    const float* __restrict__ ff2_w, const float* __restrict__ ff2_b,
    const float* __restrict__ ln_g, const float* __restrict__ ln_b,
    const float* __restrict__ fc1_w,
    float* __restrict__ table, float* __restrict__ G, float* __restrict__ Z0,
    unsigned int* __restrict__ flags, float* __restrict__ wacc)
{
    __shared__ float Gs[4096];
    __shared__ float tl[64][32];
    __shared__ float P[64][64];
    __shared__ int   kt[2048];
    __shared__ float Aa[2048];
    __shared__ float Ws[2048];
    __shared__ float red[256];
    const int tid = threadIdx.x, b = blockIdx.x;
    const int2* sp2 = reinterpret_cast<const int2*>(seq + b * L_SEQ);
    for (int j = tid; j < 2048; j += 256) kt[j] = sp2[j].x;

    if (tid < 64) {
        const int v = tid;
        float h[32], f[32];
#pragma unroll
        for (int j = 0; j < 32; ++j) { h[j] = embed[v * 32 + j]; f[j] = 0.f; }
        for (int k = 0; k < 64; ++k) {
            float z = ff1_b[k];
#pragma unroll
            for (int j = 0; j < 32; ++j) z += h[j] * ff1_w[k * 32 + j];
            z = fmaxf(z, 0.f);
#pragma unroll
            for (int j = 0; j < 32; ++j) f[j] += z * ff2_w[j * 64 + k];
        }
        float x[32], mu = 0.f;
#pragma unroll
        for (int j = 0; j < 32; ++j) { x[j] = h[j] + f[j] + ff2_b[j]; mu += x[j]; }
        mu *= (1.f / 32.f);
        float var = 0.f;
#pragma unroll
        for (int j = 0; j < 32; ++j) { float d = x[j] - mu; var += d * d; }
        var *= (1.f / 32.f);
        const float inv = rsqrtf(var + 1e-5f);
#pragma unroll
        for (int j = 0; j < 32; ++j) {
            float tv = ln_g[j] * (x[j] - mu) * inv + ln_b[j];
            tl[v][j] = tv;
            if (b == 0) table[v * 32 + j] = tv;
        }
    }
    __syncthreads();

    for (int idx = tid; idx < 4096; idx += 256) {
        const int v = idx >> 6, u = idx & 63;
        float acc = 0.f;
#pragma unroll
        for (int j = 0; j < 32; ++j) acc += tl[v][j] * tl[u][j];
        Gs[idx] = acc;
        if (b == 0) G[idx] = acc;
    }
    if (b == 0) {
        for (int idx = tid; idx < 512; idx += 256) {
            const int v = idx >> 3, i = idx & 7;
            float acc = 0.f;
#pragma unroll
            for (int j = 0; j < 32; ++j) acc += fc1_w[i * 32 + j] * tl[v][j];
            Z0[idx] = acc;
        }
    }
    __syncthreads();

    for (int idx = tid; idx < 4096; idx += 256) {
        const int c = idx >> 6, u = idx & 63;
        const int base = c * 32;
        float s = 0.f;
#pragma unroll 4
        for (int j = 0; j < 32; ++j) s += Gs[kt[base + j] * 64 + u];
        P[c][u] = s;
    }
    __syncthreads();
    if (tid < 64) {
        float acc = 0.f;
        for (int c = 0; c < 64; ++c) { float p = P[c][tid]; P[c][tid] = acc; acc += p; }
    }
    __syncthreads();
    for (int t = tid; t < NSTEP; t += 256) {
        const int c = t >> 5, base = c << 5;
        const int ktt = kt[t];
        float a = P[c][ktt];
        for (int s = base; s < t; ++s) a += Gs[kt[s] * 64 + ktt];
        Aa[t] = a;
        Ws[t] = 2.f * a + Gs[ktt * 65];
    }
    __syncthreads();
    float loc[8], tot = 0.f;
    const int base8 = tid * 8;
#pragma unroll
    for (int j = 0; j < 8; ++j) {
        float v = (base8 + j < NSTEP) ? Ws[base8 + j] : 0.f;
        loc[j] = tot; tot += v;
    }
    red[tid] = tot;
    __syncthreads();
    float run = tot;
    for (int off = 1; off < 256; off <<= 1) {
        float add = (tid >= off) ? red[tid - off] : 0.f;
        __syncthreads();
        run += add; red[tid] = run;
        __syncthreads();
    }
    const float excl = run - tot;
    __syncthreads();
#pragma unroll
    for (int j = 0; j < 8; ++j) {
        const int t = base8 + j;
        if (t < NSTEP) {
            const float u_t = excl + loc[j];
            const float tf = (float)t;
            const int ktt = kt[t];
            const float r = fmaf(tf * tf, Gs[ktt * 65] - 16.f, u_t)
                            - 2.f * tf * Aa[t];
            Ws[t] = (t == 0 || r > 0.f) ? 1.f : 0.f;
        }
    }
    __syncthreads();
    int cnt = 0;
    if (tid < 64) {
        unsigned int w = 0;
        for (int j = 0; j < 32; ++j) {
            const int t = tid * 32 + j;
            if (t < NSTEP && Ws[t] != 0.f) w |= 1u << j;
        }
        flags[b * 64 + tid] = w;
        cnt = __popc(w);
    }
    red[tid] = (float)cnt;
    __syncthreads();
    if (tid == 0) {
        float s = 0.f;
        for (int j = 0; j < 64; ++j) s += red[j];
        atomicAdd(wacc, s);
    }
}

// ---------------------------------------------------------------------------
// Phase B2: fast-weight scan. One wave per batch row, 256 blocks (1/CU).
// 2048 steps (last is a flag-0 no-op), outer 64 x fully-unrolled 32.
// Plain-C DS (compiler schedules waits); single-asm sel8u; b1-post fold.
// ---------------------------------------------------------------------------
__global__ __launch_bounds__(64) void scan_kernel(
    const int* __restrict__ seq, const float* __restrict__ tableg,
    const float* __restrict__ Gg, const float* __restrict__ Z0g,
    const float* __restrict__ fc1_b, const float* __restrict__ fc2_w,
    const float* __restrict__ fc2_b, const float* __restrict__ out_w,
    const float* __restrict__ out_b, const unsigned int* __restrict__ flags,
    const float* __restrict__ wacc, float* __restrict__ out)
{
    __shared__ float Gs[4096];
    __shared__ float tabs[2048];
    __shared__ float ctx_s[32];
    const int b = blockIdx.x, tid = threadIdx.x;
    const int i = tid & 7, g = tid >> 3;
    const int l31 = tid & 31;
    const int i4 = i << 2;

    if (b == 0 && tid == 0) out[16384] = wacc[0] * (1.0f / 524032.0f);

    for (int idx = tid; idx < 4096; idx += 64) Gs[idx] = Gg[idx];
    for (int idx = tid; idx < 2048; idx += 64) tabs[idx] = tableg[idx];
    __syncthreads();
    const f32x4* tab4 = reinterpret_cast<const f32x4*>(tabs);

    // --- state ---
    float Zr[8];
#pragma unroll
    for (int r = 0; r < 8; ++r) Zr[r] = Z0g[(8 * g + r) * 8 + i];
    float b1 = fc1_b[i];
    float W2r0 = fc2_w[(4 * g + 0) * 8 + i];
    float W2r1 = fc2_w[(4 * g + 1) * 8 + i];
    float W2r2 = fc2_w[(4 * g + 2) * 8 + i];
    float W2r3 = fc2_w[(4 * g + 3) * 8 + i];
    f32x4 b2r = *reinterpret_cast<const f32x4*>(fc2_b + 4 * g);

    const int2* sp2 = reinterpret_cast<const int2*>(seq + b * L_SEQ);
    const unsigned int fwv = flags[b * 64 + tid];   // lane l holds flag word l

    int2 cbA = sp2[l31];          // chunk c
    int2 cbB = sp2[32 + l31];     // chunk c+1
    int2 cbC;                     // chunk c+2 (prefetched per chunk)

    // --- prologue (t = 0) ---
    int kS = rli(cbA.x, 0);
    int vS = rli(cbA.y, 0);
    const f32x4* gp0 = reinterpret_cast<const f32x4*>(Gs + kS * 64 + 8 * g);
    f32x4 GaC = gp0[0], GbC = gp0[1];
    f32x4 vc0 = tab4[vS * 8 + g];
    float yb = bperm_row(kS, i4, sel8u(Zr, kS & 7)) + b1;
    float es0 = b2r.x - vc0.x, es1 = b2r.y - vc0.y;
    float es2 = b2r.z - vc0.z, es3 = b2r.w - vc0.w;
    float c_prev = 0.f, gB1c = 0.f;

    for (int c = 0; c < 64; ++c) {
        const unsigned int fw = (unsigned int)rli((int)fwv, c);
        {   // prefetch chunk c+2 tokens (1 global load / 32 steps)
            int c2 = c + 2; if (c2 > 63) c2 = 63;
            cbC = sp2[c2 * 32 + l31];
        }
#pragma unroll
        for (int j = 0; j < 32; ++j) {
            // token for step t+1 — compile-time lane index
            int kN, vN;
            if (j < 31) { kN = rli(cbA.x, j + 1); vN = rli(cbA.y, j + 1); }
            else        { kN = rli(cbB.x, 0);     vN = rli(cbB.y, 0); }
            const float st = ((fw >> j) & 1u) ? ST_W : 0.f;   // uniform SALU

            // issue ALL DS for step t+1 (plain C; compiler places waits)
            float ynv = bperm_row(kN, i4, sel8u(Zr, kN & 7)); // reads Z_{t-1}
            const f32x4* gpn =
                reinterpret_cast<const f32x4*>(Gs + kN * 64 + 8 * g);
            f32x4 GaN = gpn[0], GbN = gpn[1];
            f32x4 vcN = tab4[vN * 8 + g];
            float gbN = Gs[kS * 64 + kN];        // G[k_t][k_{t+1}]

            // --- critical path (step t) ---
            const float z1 = fmaf(c_prev, gB1c, yb);
            const float a  = fmaxf(z1, 0.f);
            float p0 = W2r0 * a, p1 = W2r1 * a, p2 = W2r2 * a, p3 = W2r3 * a;
            redi4(p0, p1, p2, p3);
            const float dp0 = p0 + es0, dp1 = p1 + es1;
            const float dp2 = p2 + es2, dp3 = p3 + es3;
            float q = redg1(fmaf(W2r0, dp0, W2r1 * dp1) +
                            fmaf(W2r2, dp2, W2r3 * dp3));
            const float cc = (z1 > 0.f) ? st * q : 0.f;

            // --- updates (off critical path) ---
            const float u0 = st * dp0, u1 = st * dp1;
            const float u2 = st * dp2, u3 = st * dp3;
            W2r0 = fmaf(u0, a, W2r0); W2r1 = fmaf(u1, a, W2r1);
            W2r2 = fmaf(u2, a, W2r2); W2r3 = fmaf(u3, a, W2r3);
            b2r.x += u0; b2r.y += u1; b2r.z += u2; b2r.w += u3;
            Zr[0] = fmaf(cc, GaC.x, Zr[0]); Zr[1] = fmaf(cc, GaC.y, Zr[1]);
            Zr[2] = fmaf(cc, GaC.z, Zr[2]); Zr[3] = fmaf(cc, GaC.w, Zr[3]);
            Zr[4] = fmaf(cc, GbC.x, Zr[4]); Zr[5] = fmaf(cc, GbC.y, Zr[5]);
            Zr[6] = fmaf(cc, GbC.z, Zr[6]); Zr[7] = fmaf(cc, GbC.w, Zr[7]);
            b1 += cc;
            // b1-post fold: yb_next = ynv + b1_post; z1_next = fma(cc, gbN, yb)
            const float ybN = ynv + b1;
            es0 = b2r.x - vcN.x; es1 = b2r.y - vcN.y;   // es for step t+1
            es2 = b2r.z - vcN.z; es3 = b2r.w - vcN.w;

            // --- rotate (renamed by unroll) ---
            yb = ybN; c_prev = cc; gB1c = gbN;
            GaC = GaN; GbC = GbN; kS = kN;
        }
        cbA = cbB; cbB = cbC;
    }

    // --- query/context (state = after the 2047 real steps) ---
    const int tq = seq[b * L_SEQ + (L_SEQ - 1)];
    float yq = bperm_row(tq, i4, sel8u(Zr, tq & 7));
    const float zq = yq + b1;
    const float aq = fmaxf(zq, 0.f);
    float c0 = W2r0 * aq, c1 = W2r1 * aq, c2 = W2r2 * aq, c3 = W2r3 * aq;
    redi4(c0, c1, c2, c3);
    if (i == 0) {
        ctx_s[4 * g + 0] = c0 + b2r.x;
        ctx_s[4 * g + 1] = c1 + b2r.y;
        ctx_s[4 * g + 2] = c2 + b2r.z;
        ctx_s[4 * g + 3] = c3 + b2r.w;
    }
    __syncthreads();

    float acc = out_b[tid];
#pragma unroll
    for (int j = 0; j < 32; ++j) acc += ctx_s[j] * out_w[tid * 32 + j];
    out[b * 64 + tid] = acc;
}

// ---------------------------------------------------------------------------
extern "C" void kernel_launch(void* const* d_in, const int* in_sizes, int n_in,
                              void* d_out, int out_size, void* d_ws, size_t ws_size,
                              hipStream_t stream)
{
    const int*   seq   = (const int*)  d_in[0];
    const float* embed = (const float*)d_in[1];
    const float* ff1_w = (const float*)d_in[2];
    const float* ff1_b = (const float*)d_in[3];
    const float* ff2_w = (const float*)d_in[4];
    const float* ff2_b = (const float*)d_in[5];
    const float* ln_g  = (const float*)d_in[6];
    const float* ln_b  = (const float*)d_in[7];
    const float* fc1_w = (const float*)d_in[8];
    const float* fc1_b = (const float*)d_in[9];
    const float* fc2_w = (const float*)d_in[10];
    const float* fc2_b = (const float*)d_in[11];
    const float* out_w = (const float*)d_in[12];
    const float* out_b = (const float*)d_in[13];

    float* out = (float*)d_out;
    char* ws = (char*)d_ws;
    float*        table = (float*)(ws + 0);
    float*        G     = (float*)(ws + 8192);
    float*        Z0    = (float*)(ws + 24576);
    float*        wacc  = (float*)(ws + 26624);
    unsigned int* flags = (unsigned int*)(ws + 28672);

    hipMemsetAsync(wacc, 0, sizeof(float), stream);
    hipLaunchKernelGGL(flags_kernel, dim3(256), dim3(256), 0, stream,
                       seq, embed, ff1_w, ff1_b, ff2_w, ff2_b, ln_g, ln_b,
                       fc1_w, table, G, Z0, flags, wacc);
    hipLaunchKernelGGL(scan_kernel, dim3(256), dim3(64), 0, stream,
                       seq, table, G, Z0, fc1_b, fc2_w, fc2_b,
                       out_w, out_b, flags, wacc, out);
}